// Round 7
// baseline (279.918 us; speedup 1.0000x reference)
//
#include <hip/hip_runtime.h>
#include <hip/hip_bf16.h>

// fp32 problem: b=2, s=2048, D=2048, 32 q-heads / 8 kv-groups, d=64
#define TOKENS   4096
#define SEQ      2048
#define DMODEL   2048
#define CONCAT   3072
#define NHEADS   32
#define NGROUPS  8
#define HPERG    4
#define CQ       2048
#define CK       512

typedef __attribute__((ext_vector_type(8))) short bf16x8;
typedef __attribute__((ext_vector_type(4))) float f32x4;

__device__ __forceinline__ ushort f2bf(float f) {
    __hip_bfloat16 h = __float2bfloat16(f);
    return __builtin_bit_cast(ushort, h);
}

// packed f32x2 -> bf16x2 (RNE), dst = bf16(hi)<<16 | bf16(lo)
__device__ __forceinline__ uint cvt_pk_bf16(float lo, float hi) {
    uint r;
    asm("v_cvt_pk_bf16_f32 %0, %1, %2" : "=v"(r) : "v"(lo), "v"(hi));
    return r;
}

#define GLOBAL_TO_LDS16(g, l)                                                  \
    __builtin_amdgcn_global_load_lds(                                          \
        (const __attribute__((address_space(1))) void*)(g),                    \
        (__attribute__((address_space(3))) void*)(l), 16, 0, 0)

// ---------------- RoPE cos/sin table: tab[s*32+j] = (cos, sin) ----------
// Same float path as the original pack (exp2f/cosf/sinf) -> identical
// numerics.  512 KB, consumed only by the gemm-in epilogue.
__global__ void rope_table_kernel(float2* __restrict__ tab) {
    int i = blockIdx.x * 256 + threadIdx.x;      // 65536 = 2048 * 32
    int s = i >> 5, j = i & 31;
    const float LOG2_THETA = 13.287712379549449f;
    float inv = exp2f(-((float)j / 32.0f) * LOG2_THETA);
    float ang = (float)s * inv;
    tab[i] = make_float2(cosf(ang), sinf(ang));
}

// ---------------- RMSNorm: one block (256 thr) per token, bf16 out -------
__global__ void rmsnorm_kernel(const float* __restrict__ x,
                               const float* __restrict__ w,
                               ushort* __restrict__ y_bf) {
    int t = blockIdx.x;
    const float4* xr = (const float4*)(x + (size_t)t * DMODEL);
    float4 v[2];
    float ss = 0.f;
#pragma unroll
    for (int i = 0; i < 2; i++) {
        v[i] = xr[threadIdx.x + i * 256];
        ss += v[i].x * v[i].x + v[i].y * v[i].y + v[i].z * v[i].z + v[i].w * v[i].w;
    }
#pragma unroll
    for (int off = 32; off >= 1; off >>= 1) ss += __shfl_xor(ss, off);
    __shared__ float red[4];
    int wid = threadIdx.x >> 6;
    if ((threadIdx.x & 63) == 0) red[wid] = ss;
    __syncthreads();
    float total = red[0] + red[1] + red[2] + red[3];
    float scale = rsqrtf(total * (1.0f / DMODEL) + 1e-6f);
    const float4* wr = (const float4*)w;
    ushort4* yr = (ushort4*)(y_bf + (size_t)t * DMODEL);
#pragma unroll
    for (int i = 0; i < 2; i++) {
        int c = threadIdx.x + i * 256;
        float4 wv = wr[c];
        ushort4 o;
        o.x = f2bf(v[i].x * scale * wv.x);
        o.y = f2bf(v[i].y * scale * wv.y);
        o.z = f2bf(v[i].z * scale * wv.z);
        o.w = f2bf(v[i].w * scale * wv.w);
        yr[c] = o;
    }
}

// ---------------- fp32 -> bf16 cast, both weight matrices ---------------
#define N4_WIN  (CONCAT * DMODEL / 4)
#define N4_WOUT (DMODEL * DMODEL / 4)
__global__ void pack_weights_kernel(const float* __restrict__ w_in,
                                    const float* __restrict__ w_out,
                                    ushort* __restrict__ w_in_bf,
                                    ushort* __restrict__ w_out_bf) {
    int i = blockIdx.x * 256 + threadIdx.x;
    const float* src;
    ushort* dst;
    int j;
    if (i < N4_WIN) { src = w_in; dst = w_in_bf; j = i; }
    else if (i < N4_WIN + N4_WOUT) { src = w_out; dst = w_out_bf; j = i - N4_WIN; }
    else return;
    float4 v = ((const float4*)src)[j];
    ushort4 o;
    o.x = f2bf(v.x); o.y = f2bf(v.y); o.z = f2bf(v.z); o.w = f2bf(v.w);
    ((ushort4*)dst)[j] = o;
}

// ---------------- 256xBN 8-phase MFMA GEMM -------------------------------
// C[M,N] = A[M,K] * B[N,K]^T, bf16 in.  BN = 128*NFRAG.
// 512 thr = 8 waves (2M x 4N); wave tile 128 x (32*NFRAG); BK=64.
// Rolling half-tile buffer, counted vmcnt (6 / 4), raw s_barrier.
// LDS swizzle: linear dest + pre-swizzled global src.
// T1: XCD-aware block swizzle (nwg%8==0 for both call sites -> bijective).
// EPI=1: OUT = X + acc (f32).
// EPI=2 (NFRAG=2, gemm-in only): fused RoPE+bf16 pack from acc into
// Qb/Kb/Vb; qkv f32 never materialized.  cos/sin from the precomputed
// global table (no libm in-epilogue -> no spills around live acc).
// Q/K stored in PAIRED-COLUMN layout: row dword j' = (col j', col j'+32)
// packed by v_cvt_pk_bf16_f32 -> 64 coalesced dword stores per thread.
// Both Q and K use the identical d-permutation, so QK^T over d is
// invariant and the attention kernel is unchanged.
// V packed along s (r-pairs consecutive) -> dword stores, 16B/d segments.
#define LGKM(nn) asm volatile("s_waitcnt lgkmcnt(" #nn ")" ::: "memory")
#define VMC(nn)  asm volatile("s_waitcnt vmcnt(" #nn ")" ::: "memory")
#define SBAR()   __builtin_amdgcn_s_barrier()
#define SCHED0() __builtin_amdgcn_sched_barrier(0)
#define PRIO(p)  __builtin_amdgcn_s_setprio(p)

#define RD_A(mh)                                                              \
    _Pragma("unroll") for (int mi = 0; mi < 4; mi++)                          \
    _Pragma("unroll") for (int ks = 0; ks < 2; ks++)                          \
        af[mi][ks] = *(const bf16x8*)(Ab +                                    \
            ((arow0 + (mh) * 64 + mi * 16) * 8 +                              \
             ((ks * 4 + quad) ^ an)) * 8);

#define RD_B(nh)                                                              \
    _Pragma("unroll") for (int ni = 0; ni < NFRAG; ni++)                      \
    _Pragma("unroll") for (int ks = 0; ks < 2; ks++)                          \
        bfr[nh][ni][ks] = *(const bf16x8*)(Bb +                               \
            ((brow0 + (nh) * (16 * NFRAG) + ni * 16) * 8 +                    \
             ((ks * 4 + quad) ^ an)) * 8);

#define MMQ(mh, nh)                                                           \
    _Pragma("unroll") for (int mi = 0; mi < 4; mi++)                          \
    _Pragma("unroll") for (int ni = 0; ni < NFRAG; ni++)                      \
    _Pragma("unroll") for (int ks = 0; ks < 2; ks++)                          \
        acc[(mh) * 4 + mi][(nh) * NFRAG + ni] =                               \
            __builtin_amdgcn_mfma_f32_16x16x32_bf16(af[mi][ks],               \
                bfr[nh][ni][ks], acc[(mh) * 4 + mi][(nh) * NFRAG + ni],       \
                0, 0, 0);

#define ISSUE_HALF(H_)                                                        \
    {                                                                         \
        int H = (H_);                                                         \
        if (H < 4 * NT) {                                                     \
            int t2 = H >> 2, j2 = H & 3;                                      \
            int k0 = t2 << 6;                                                 \
            if (j2 == 0 || j2 == 3) {                                         \
                int half = (j2 == 3);                                         \
                ushort* lb = (ushort*)&As[t2 & 1][0];                         \
                _Pragma("unroll") for (int c = 0; c < 2; c++) {               \
                    int s = w * 2 + c;                                        \
                    int row = (s >> 3) * 128 + half * 64 + (s & 7) * 8;       \
                    const ushort* g = Aptr +                                  \
                        (size_t)(bm + row + l8) * K + k0 + kb8;               \
                    GLOBAL_TO_LDS16(g, lb + row * 64);                        \
                }                                                             \
            } else {                                                          \
                int half = (j2 == 2);                                         \
                ushort* lb = (ushort*)&Bs[t2 & 1][0];                         \
                if constexpr (NFRAG == 2) {                                   \
                    _Pragma("unroll") for (int c = 0; c < 2; c++) {           \
                        int s = w * 2 + c;                                    \
                        int row = (s >> 2) * 64 + half * 32 + (s & 3) * 8;    \
                        const ushort* g = Bptr +                              \
                            (size_t)(bn + row + l8) * K + k0 + kb8;           \
                        GLOBAL_TO_LDS16(g, lb + row * 64);                    \
                    }                                                         \
                } else {                                                      \
                    int row = (w >> 1) * 32 + half * 16 + (w & 1) * 8;        \
                    const ushort* g = Bptr +                                  \
                        (size_t)(bn + row + l8) * K + k0 + kb8;               \
                    GLOBAL_TO_LDS16(g, lb + row * 64);                        \
                }                                                             \
            }                                                                 \
        }                                                                     \
    }

#define VMC_STEADY()                                                          \
    { if constexpr (NFRAG == 2) { VMC(6); } else { VMC(4); } }

#define TILE(t_, BUF)                                                         \
    {                                                                         \
        const ushort* Ab = &As[BUF][0];                                       \
        const ushort* Bb = &Bs[BUF][0];                                       \
        /* phase 1: A0,B0 -> Q(0,0) */                                        \
        RD_A(0); RD_B(0);                                                     \
        ISSUE_HALF(4 * (t_) + 7);                                             \
        LGKM(8);                                                              \
        SBAR(); LGKM(0); SCHED0();                                            \
        PRIO(1); MMQ(0, 0); PRIO(0);                                          \
        SBAR();                                                               \
        /* phase 2: B1 -> Q(0,1) */                                           \
        RD_B(1);                                                              \
        ISSUE_HALF(4 * (t_) + 8);                                             \
        SBAR(); LGKM(0); SCHED0();                                            \
        PRIO(1); MMQ(0, 1); PRIO(0);                                          \
        SBAR();                                                               \
        /* phase 3: A1 -> Q(1,0) */                                           \
        RD_A(1);                                                              \
        ISSUE_HALF(4 * (t_) + 9);                                             \
        SBAR(); LGKM(0); SCHED0();                                            \
        PRIO(1); MMQ(1, 0); PRIO(0);                                          \
        SBAR();                                                               \
        /* phase 4: Q(1,1) + tile-boundary counted vmcnt */                   \
        ISSUE_HALF(4 * (t_) + 10);                                            \
        SBAR(); SCHED0();                                                     \
        PRIO(1); MMQ(1, 1); PRIO(0);                                          \
        if ((t_) + 2 < NT)        { VMC_STEADY(); }                           \
        else if ((t_) + 2 == NT)  { VMC(0); }                                 \
        SBAR();                                                               \
    }

template <int EPI, int NFRAG>
__global__ __launch_bounds__(512, 2) void gemm_nt_8ph(
        const ushort* __restrict__ Aptr, const ushort* __restrict__ Bptr,
        const float* __restrict__ X, float* __restrict__ OUT,
        ushort* __restrict__ Qb_, ushort* __restrict__ Kb_,
        ushort* __restrict__ Vb_, const float2* __restrict__ Tab,
        int M, int N, int K) {
    __shared__ __align__(16) ushort As[2][256 * 64];
    __shared__ __align__(16) ushort Bs[2][NFRAG * 128 * 64];

    // XCD-aware swizzle: XCD k owns a contiguous chunk of tile space.
    int nwg = (int)(gridDim.x * gridDim.y);
    int lin = (int)(blockIdx.y * gridDim.x + blockIdx.x);
    int swz = lin;
    if ((nwg & 7) == 0) swz = (lin & 7) * (nwg >> 3) + (lin >> 3);
    const int bm = (swz / (int)gridDim.x) * 256;
    const int bn = (swz % (int)gridDim.x) * (128 * NFRAG);

    const int w = threadIdx.x >> 6, lane = threadIdx.x & 63;
    const int n = lane & 15, quad = lane >> 4;
    const int wm = w >> 2, wn = w & 3;
    const int an = n & 7;
    const int l8 = lane >> 3;
    const int kb8 = ((lane & 7) ^ l8) * 8;
    const int arow0 = wm * 128 + n;
    const int brow0 = wn * (32 * NFRAG) + n;
    const int NT = K >> 6;

    f32x4 acc[8][2 * NFRAG] = {};
    bf16x8 af[4][2], bfr[2][NFRAG][2];

    // prologue: pre-issue 7 halves (queue order), land first 4, barrier
    ISSUE_HALF(0); ISSUE_HALF(1); ISSUE_HALF(2); ISSUE_HALF(3);
    ISSUE_HALF(4); ISSUE_HALF(5); ISSUE_HALF(6);
    VMC_STEADY();
    SBAR();

    for (int tt = 0; tt < NT; tt += 2) {
        TILE(tt, 0);
        TILE(tt + 1, 1);
    }

    if constexpr (EPI == 2) {
        // ---- fused RoPE + pack epilogue (NFRAG==2 only) ----
        const int bq = bm >> 11;           // batch (BM=256 divides 2048)
        const int s0 = bm & 2047;          // first seq pos of this block
        int col0 = bn + wn * 64;           // wave's head base (one full head)
        int slb = wm * 128 + quad * 4;
        if (col0 < CQ + CK) {
            bool isQ = col0 < CQ;
            ushort* base;
            if (isQ) {
                int head = col0 >> 6;
                base = Qb_ + ((size_t)((bq * 8 + (head >> 2)) * 4 + (head & 3))
                              * SEQ) * 64;
            } else {
                int kh = (col0 - CQ) >> 6;
                base = Kb_ + ((size_t)(bq * 8 + kh) * SEQ) * 64;
            }
            const float QS = 0.18033688011112042f;   // 0.125 * log2(e)
#pragma unroll
            for (int mi = 0; mi < 8; mi++)
#pragma unroll
                for (int r = 0; r < 4; r++) {
                    int s = s0 + slb + mi * 16 + r;
                    float2 t0 = Tab[(size_t)s * 32 + n];
                    float2 t1 = Tab[(size_t)s * 32 + n + 16];
                    float o1a = acc[mi][0][r] * t0.x - acc[mi][2][r] * t0.y;
                    float o2a = acc[mi][2][r] * t0.x + acc[mi][0][r] * t0.y;
                    float o1b = acc[mi][1][r] * t1.x - acc[mi][3][r] * t1.y;
                    float o2b = acc[mi][3][r] * t1.x + acc[mi][1][r] * t1.y;
                    if (isQ) { o1a *= QS; o2a *= QS; o1b *= QS; o2b *= QS; }
                    uint* drow = (uint*)(base + (size_t)s * 64);
                    drow[n]      = cvt_pk_bf16(o1a, o2a);   // cols (n, n+32)
                    drow[16 + n] = cvt_pk_bf16(o1b, o2b);   // cols (n+16, n+48)
                }
        } else {
            int vh = (col0 - CQ - CK) >> 6;
            ushort* vb = Vb_ + (size_t)(bq * 8 + vh) * 64 * SEQ;
#pragma unroll
            for (int mi = 0; mi < 8; mi++)
#pragma unroll
                for (int ni = 0; ni < 2 * NFRAG; ni++) {
                    int d = ni * 16 + n;
                    int s = s0 + slb + mi * 16;
                    uint* dst = (uint*)(vb + (size_t)d * SEQ + s);
                    dst[0] = cvt_pk_bf16(acc[mi][ni][0], acc[mi][ni][1]);
                    dst[1] = cvt_pk_bf16(acc[mi][ni][2], acc[mi][ni][3]);
                }
        }
    } else {
#pragma unroll
        for (int mi = 0; mi < 8; mi++)
#pragma unroll
            for (int ni = 0; ni < 2 * NFRAG; ni++) {
                int row = bm + wm * 128 + mi * 16 + quad * 4;
                int col = bn + wn * (32 * NFRAG) + ni * 16 + n;
#pragma unroll
                for (int r = 0; r < 4; r++) {
                    size_t idx = (size_t)(row + r) * N + col;
                    OUT[idx] = X[idx] + acc[mi][ni][r];
                }
            }
    }
}

// ---------------- MFMA flash attention, v4 -------------------------------
// Block = (b,g,h, 128-query tile); 8 waves x 16 query rows each.
// No-max exp2 softmax (Q pre-scaled): p = v_exp(S2), l = ones-column MFMA.
// S^T via operand swap -> consecutive keys in-lane -> packed-dword P writes.
// K/V staged by direct global_load_lds, double-buffered, counted vmcnt(2).
// Conflict-free reads via XOR on the GLOBAL source (both-sides-or-neither).
// P per-wave LDS: dwords ((key>>3)*17 + q)*4 + ((key&7)>>1), q in [0,16).
// NOTE: Q and K arrive in the gemm-in epilogue's paired-column layout;
// since both share it, QK^T over d is unchanged.
#define AISSUE(kt_, buf_)                                                     \
    {                                                                         \
        const ushort* Kg_ = Kg0 + (kt_) * 64 * 64;                            \
        const ushort* Vg_ = Vg0 + (kt_) * 64;                                 \
        GLOBAL_TO_LDS16(Kg_ + (w * 8 + l3) * 64 + lx * 8,                     \
                        &Kl[buf_][(size_t)threadIdx.x * 8]);                  \
        GLOBAL_TO_LDS16(Vg_ + (size_t)(w * 8 + l3) * SEQ + lx * 8,            \
                        &Vl[buf_][(size_t)threadIdx.x * 8]);                  \
    }

__global__ __launch_bounds__(512) void attn_mfma_kernel(
        const ushort* __restrict__ Qb, const ushort* __restrict__ Kb,
        const ushort* __restrict__ Vb, ushort* __restrict__ o_bf) {
    __shared__ __align__(16) ushort Kl[2][512 * 8];
    __shared__ __align__(16) ushort Vl[2][512 * 8];
    __shared__ __align__(16) uint   Pl[8][544];

    int blk = blockIdx.x;
    int qt  = 15 - (blk >> 6);          // longest blocks dispatch first
    int bgh = blk & 63;
    int h = bgh & 3, g = (bgh >> 2) & 7, b = bgh >> 5;
    int w = threadIdx.x >> 6, lane = threadIdx.x & 63;
    int n = lane & 15, quad = lane >> 4;
    const int an = n & 7;
    int Q0 = qt * 128;
    int qw = Q0 + w * 16;               // wave's first query row

    // staging lane constants
    const int l3 = lane >> 3;
    const int lx = (lane & 7) ^ l3;

    const ushort* Qh  = Qb + (size_t)((b * 8 + g) * 4 + h) * (SEQ * 64);
    const ushort* Kg0 = Kb + (size_t)(b * 8 + g) * (SEQ * 64);
    const ushort* Vg0 = Vb + (size_t)(b * 8 + g) * (64 * SEQ);

    // Q fragments (rows of Q; per-lane data for B-operand use)
    bf16x8 aq[2];
#pragma unroll
    for (int ks = 0; ks < 2; ks++)
        aq[ks] = *(const bf16x8*)(
            Qh + (size_t)(qw + n) * 64 + ks * 32 + quad * 8);

    f32x4 od[4] = {};
    f32x4 od4 = {};

    short onev = (n == 0) ? (short)0x3F80 : (short)0;
    bf16x8 bones = {onev, onev, onev, onev, onev, onev, onev, onev};

    uint* Pw = Pl[w];
    int nkt = qt * 2 + 2;

    // prologue: tiles 0 and 1 in flight (2 loads each per lane)
    AISSUE(0, 0);
    AISSUE(1, 1);

    for (int kt = 0; kt < nkt; kt++) {
        int buf = kt & 1;
        if (kt + 1 < nkt) { VMC(2); } else { VMC(0); }
        SBAR(); SCHED0();                // buf[kt&1] fully loaded, all waves

        bool act = (kt * 64 <= qw + 15);   // do this wave's rows see kt?
        if (act) {
            const ushort* Kb_ = Kl[buf];
            const ushort* Vb_ = Vl[buf];

            // S^T = K Q^T (operand swap), exp2, cvt_pk, P write
#pragma unroll
            for (int t16k = 0; t16k < 4; t16k++) {
                int krow = (t16k * 16 + n) * 8;
                bf16x8 kf0 = *(const bf16x8*)(Kb_ + (krow + (quad ^ an)) * 8);
                bf16x8 kf1 = *(const bf16x8*)(Kb_ + (krow + ((quad + 4) ^ an)) * 8);
                int key0 = kt * 64 + t16k * 16 + quad * 4;
                f32x4 c = {};
                PRIO(1);
                c = __builtin_amdgcn_mfma_f32_16x16x32_bf16(kf0, aq[0], c, 0, 0, 0);
                c = __builtin_amdgcn_mfma_f32_16x16x32_bf16(kf1, aq[1], c, 0, 0, 0);
                PRIO(0);
                int qrow = qw + n;
                float p[4];
                if (kt * 64 + 63 > qw) {             // tile may mask
#pragma unroll
                    for (int r = 0; r < 4; r++)
                        p[r] = (key0 + r <= qrow) ? __builtin_amdgcn_exp2f(c[r]) : 0.f;
                } else {
#pragma unroll
                    for (int r = 0; r < 4; r++)
                        p[r] = __builtin_amdgcn_exp2f(c[r]);
                }
                uint d0 = cvt_pk_bf16(p[0], p[1]);
                uint d1 = cvt_pk_bf16(p[2], p[3]);
                int base = ((t16k * 2 + (quad >> 1)) * 17 + n) * 4
                           + (quad & 1) * 2;
                Pw[base]     = d0;
                Pw[base + 1] = d1;
            }

            // O += P V   (+ ones column accumulates l)
#pragma unroll
            for (int kb2 = 0; kb2 < 2; kb2++) {
                int kb = kb2 * 4 + quad;
                bf16x8 bv[4];
#pragma unroll
                for (int dt = 0; dt < 4; dt++)
                    bv[dt] = *(const bf16x8*)(Vb_ +
                        (((dt * 16 + n) * 8 + (kb ^ an)) * 8));
                bf16x8 ap = *(const bf16x8*)(
                    (const ushort*)Pw + ((kb2 * 4 + quad) * 17 + n) * 8);
                PRIO(1);
#pragma unroll
                for (int dt = 0; dt < 4; dt++)
                    od[dt] = __builtin_amdgcn_mfma_f32_16x16x32_bf16(
                        ap, bv[dt], od[dt], 0, 0, 0);
                od4 = __builtin_amdgcn_mfma_f32_16x16x32_bf16(
                    ap, bones, od4, 0, 0, 0);
                PRIO(0);
            }
        }

        SCHED0(); SBAR();                // all reads of buf done
        if (kt + 2 < nkt) AISSUE(kt + 2, buf);
    }

    // epilogue: l lives in column 0 of od4 (lane n==0); broadcast, divide
    float linv[4];
#pragma unroll
    for (int r = 0; r < 4; r++) {
        float lv = __shfl(od4[r], lane & 48);
        linv[r] = __builtin_amdgcn_rcpf(lv);
    }
#pragma unroll
    for (int dt = 0; dt < 4; dt++)
#pragma unroll
        for (int r = 0; r < 4; r++) {
            int q = qw + quad * 4 + r;
            int col = (g * 4 + h) * 64 + dt * 16 + n;
            o_bf[(size_t)(b * SEQ + q) * DMODEL + col] =
                f2bf(od[dt][r] * linv[r]);
        }
}

extern "C" void kernel_launch(void* const* d_in, const int* in_sizes, int n_in,
                              void* d_out, int out_size, void* d_ws, size_t ws_size,
                              hipStream_t stream) {
    const float* x     = (const float*)d_in[0];
    const float* w_in  = (const float*)d_in[1];
    const float* w_out = (const float*)d_in[2];
    const float* rms_w = (const float*)d_in[3];
    float* out = (float*)d_out;

    // Workspace layout (76 MB):
    //   [0,16)   Qb bf16      [16,20) Kb     [20,24) Vb
    //   [24,40)  o_bf bf16    (rope_tab f32x2 512KB aliases o_bf head:
    //                          tab live only until gemm-in ends; o_bf
    //                          written first by attention, after gemm-in)
    //   [40,48)  w_out_bf     [48,64) y_bf   [64,76) w_in_bf
    const size_t MB = 1024 * 1024;
    char* ws = (char*)d_ws;
    ushort* Qb       = (ushort*)ws;
    ushort* Kb       = (ushort*)(ws + 16 * MB);
    ushort* Vb       = (ushort*)(ws + 20 * MB);
    ushort* o_bf     = (ushort*)(ws + 24 * MB);
    float2* rope_tab = (float2*)(ws + 24 * MB);
    ushort* w_out_bf = (ushort*)(ws + 40 * MB);
    ushort* y_bf     = (ushort*)(ws + 48 * MB);
    ushort* w_in_bf  = (ushort*)(ws + 64 * MB);

    rope_table_kernel<<<256, 256, 0, stream>>>(rope_tab);
    rmsnorm_kernel<<<TOKENS, 256, 0, stream>>>(x, rms_w, y_bf);
    pack_weights_kernel<<<(N4_WIN + N4_WOUT + 255) / 256, 256, 0, stream>>>(
        w_in, w_out, w_in_bf, w_out_bf);

    // GEMM-in with fused RoPE/pack epilogue: writes Qb/Kb/Vb directly.
    gemm_nt_8ph<2, 2><<<dim3(CONCAT / 256, TOKENS / 256), 512, 0, stream>>>(
        y_bf, w_in_bf, nullptr, nullptr, Qb, Kb, Vb, rope_tab,
        TOKENS, CONCAT, DMODEL);

    attn_mfma_kernel<<<1024, 512, 0, stream>>>(Qb, Kb, Vb, o_bf);

    gemm_nt_8ph<1, 1><<<dim3(DMODEL / 128, TOKENS / 256), 512, 0, stream>>>(
        o_bf, w_out_bf, x, out, nullptr, nullptr, nullptr, nullptr,
        TOKENS, DMODEL, DMODEL);
}

// Round 8
// 277.724 us; speedup vs baseline: 1.0079x; 1.0079x over previous
//
#include <hip/hip_runtime.h>
#include <hip/hip_bf16.h>

// fp32 problem: b=2, s=2048, D=2048, 32 q-heads / 8 kv-groups, d=64
#define TOKENS   4096
#define SEQ      2048
#define DMODEL   2048
#define CONCAT   3072
#define NHEADS   32
#define NGROUPS  8
#define HPERG    4
#define CQ       2048
#define CK       512

typedef __attribute__((ext_vector_type(8))) short bf16x8;
typedef __attribute__((ext_vector_type(4))) float f32x4;

__device__ __forceinline__ ushort f2bf(float f) {
    __hip_bfloat16 h = __float2bfloat16(f);
    return __builtin_bit_cast(ushort, h);
}

// packed f32x2 -> bf16x2 (RNE), dst = bf16(hi)<<16 | bf16(lo)
__device__ __forceinline__ uint cvt_pk_bf16(float lo, float hi) {
    uint r;
    asm("v_cvt_pk_bf16_f32 %0, %1, %2" : "=v"(r) : "v"(lo), "v"(hi));
    return r;
}

#define GLOBAL_TO_LDS16(g, l)                                                  \
    __builtin_amdgcn_global_load_lds(                                          \
        (const __attribute__((address_space(1))) void*)(g),                    \
        (__attribute__((address_space(3))) void*)(l), 16, 0, 0)

// ---------------- prep: rope table + RMSNorm + weight packs (1 launch) ---
// blocks [0,256):        rope tab[s*32+j] = (cos,sin)  (same libm path as
//                        original pack -> identical numerics)
// blocks [256,4352):     RMSNorm token t = blk-256, bf16 out
// blocks [4352,14592):   w_in / w_out fp32->bf16 casts
#define PREP_ROPE 256
#define PREP_RMS  (PREP_ROPE + TOKENS)
#define N4_WIN  (CONCAT * DMODEL / 4)
#define N4_WOUT (DMODEL * DMODEL / 4)
#define PREP_TOTAL (PREP_RMS + (N4_WIN + N4_WOUT + 255) / 256)

__global__ void prep_kernel(const float* __restrict__ x,
                            const float* __restrict__ rms_w,
                            const float* __restrict__ w_in,
                            const float* __restrict__ w_out,
                            ushort* __restrict__ y_bf,
                            ushort* __restrict__ w_in_bf,
                            ushort* __restrict__ w_out_bf,
                            float2* __restrict__ tab) {
    int blk = blockIdx.x, tid = threadIdx.x;
    if (blk < PREP_ROPE) {
        int i = blk * 256 + tid;                 // 65536 = 2048 * 32
        int s = i >> 5, j = i & 31;
        const float LOG2_THETA = 13.287712379549449f;
        float inv = exp2f(-((float)j / 32.0f) * LOG2_THETA);
        float ang = (float)s * inv;
        tab[i] = make_float2(cosf(ang), sinf(ang));
    } else if (blk < PREP_RMS) {
        int t = blk - PREP_ROPE;
        const float4* xr = (const float4*)(x + (size_t)t * DMODEL);
        float4 v[2];
        float ss = 0.f;
#pragma unroll
        for (int i = 0; i < 2; i++) {
            v[i] = xr[tid + i * 256];
            ss += v[i].x * v[i].x + v[i].y * v[i].y + v[i].z * v[i].z + v[i].w * v[i].w;
        }
#pragma unroll
        for (int off = 32; off >= 1; off >>= 1) ss += __shfl_xor(ss, off);
        __shared__ float red[4];
        int wid = tid >> 6;
        if ((tid & 63) == 0) red[wid] = ss;
        __syncthreads();
        float total = red[0] + red[1] + red[2] + red[3];
        float scale = rsqrtf(total * (1.0f / DMODEL) + 1e-6f);
        const float4* wr = (const float4*)rms_w;
        ushort4* yr = (ushort4*)(y_bf + (size_t)t * DMODEL);
#pragma unroll
        for (int i = 0; i < 2; i++) {
            int c = tid + i * 256;
            float4 wv = wr[c];
            ushort4 o;
            o.x = f2bf(v[i].x * scale * wv.x);
            o.y = f2bf(v[i].y * scale * wv.y);
            o.z = f2bf(v[i].z * scale * wv.z);
            o.w = f2bf(v[i].w * scale * wv.w);
            yr[c] = o;
        }
    } else {
        int i = (blk - PREP_RMS) * 256 + tid;
        const float* src;
        ushort* dst;
        int j;
        if (i < N4_WIN) { src = w_in; dst = w_in_bf; j = i; }
        else if (i < N4_WIN + N4_WOUT) { src = w_out; dst = w_out_bf; j = i - N4_WIN; }
        else return;
        float4 v = ((const float4*)src)[j];
        ushort4 o;
        o.x = f2bf(v.x); o.y = f2bf(v.y); o.z = f2bf(v.z); o.w = f2bf(v.w);
        ((ushort4*)dst)[j] = o;
    }
}

// ---------------- 256xBN 8-phase MFMA GEMM -------------------------------
// C[M,N] = A[M,K] * B[N,K]^T, bf16 in.  BN = 128*NFRAG.
// 512 thr = 8 waves (2M x 4N); wave tile 128 x (32*NFRAG); BK=64.
// Rolling half-tile buffer, counted vmcnt (6 / 4), raw s_barrier.
// LDS swizzle: linear dest + pre-swizzled global src.
// T1: XCD-aware block swizzle (nwg%8==0 for both call sites -> bijective).
// EPI=2 (NFRAG=2, gemm-in): fused RoPE+bf16 pack from acc into Qb/Kb/Vb
//   (paired-column Q/K layout; both share the d-permutation so QK^T is
//   invariant; attention kernel unchanged).
// EPI=3 (NFRAG=1, gemm-out, OPERANDS SWAPPED: A=w_out M=DMODEL,
//   B=o_bf N=TOKENS): lane's 4 consecutive acc rows = 4 consecutive
//   out-columns at one token -> float4 residual load + float4 store.
//   Same K accumulation order as unswapped -> identical numerics.
#define LGKM(nn) asm volatile("s_waitcnt lgkmcnt(" #nn ")" ::: "memory")
#define VMC(nn)  asm volatile("s_waitcnt vmcnt(" #nn ")" ::: "memory")
#define SBAR()   __builtin_amdgcn_s_barrier()
#define SCHED0() __builtin_amdgcn_sched_barrier(0)
#define PRIO(p)  __builtin_amdgcn_s_setprio(p)

#define RD_A(mh)                                                              \
    _Pragma("unroll") for (int mi = 0; mi < 4; mi++)                          \
    _Pragma("unroll") for (int ks = 0; ks < 2; ks++)                          \
        af[mi][ks] = *(const bf16x8*)(Ab +                                    \
            ((arow0 + (mh) * 64 + mi * 16) * 8 +                              \
             ((ks * 4 + quad) ^ an)) * 8);

#define RD_B(nh)                                                              \
    _Pragma("unroll") for (int ni = 0; ni < NFRAG; ni++)                      \
    _Pragma("unroll") for (int ks = 0; ks < 2; ks++)                          \
        bfr[nh][ni][ks] = *(const bf16x8*)(Bb +                               \
            ((brow0 + (nh) * (16 * NFRAG) + ni * 16) * 8 +                    \
             ((ks * 4 + quad) ^ an)) * 8);

#define MMQ(mh, nh)                                                           \
    _Pragma("unroll") for (int mi = 0; mi < 4; mi++)                          \
    _Pragma("unroll") for (int ni = 0; ni < NFRAG; ni++)                      \
    _Pragma("unroll") for (int ks = 0; ks < 2; ks++)                          \
        acc[(mh) * 4 + mi][(nh) * NFRAG + ni] =                               \
            __builtin_amdgcn_mfma_f32_16x16x32_bf16(af[mi][ks],               \
                bfr[nh][ni][ks], acc[(mh) * 4 + mi][(nh) * NFRAG + ni],       \
                0, 0, 0);

#define ISSUE_HALF(H_)                                                        \
    {                                                                         \
        int H = (H_);                                                         \
        if (H < 4 * NT) {                                                     \
            int t2 = H >> 2, j2 = H & 3;                                      \
            int k0 = t2 << 6;                                                 \
            if (j2 == 0 || j2 == 3) {                                         \
                int half = (j2 == 3);                                         \
                ushort* lb = (ushort*)&As[t2 & 1][0];                         \
                _Pragma("unroll") for (int c = 0; c < 2; c++) {               \
                    int s = w * 2 + c;                                        \
                    int row = (s >> 3) * 128 + half * 64 + (s & 7) * 8;       \
                    const ushort* g = Aptr +                                  \
                        (size_t)(bm + row + l8) * K + k0 + kb8;               \
                    GLOBAL_TO_LDS16(g, lb + row * 64);                        \
                }                                                             \
            } else {                                                          \
                int half = (j2 == 2);                                         \
                ushort* lb = (ushort*)&Bs[t2 & 1][0];                         \
                if constexpr (NFRAG == 2) {                                   \
                    _Pragma("unroll") for (int c = 0; c < 2; c++) {           \
                        int s = w * 2 + c;                                    \
                        int row = (s >> 2) * 64 + half * 32 + (s & 3) * 8;    \
                        const ushort* g = Bptr +                              \
                            (size_t)(bn + row + l8) * K + k0 + kb8;           \
                        GLOBAL_TO_LDS16(g, lb + row * 64);                    \
                    }                                                         \
                } else {                                                      \
                    int row = (w >> 1) * 32 + half * 16 + (w & 1) * 8;        \
                    const ushort* g = Bptr +                                  \
                        (size_t)(bn + row + l8) * K + k0 + kb8;               \
                    GLOBAL_TO_LDS16(g, lb + row * 64);                        \
                }                                                             \
            }                                                                 \
        }                                                                     \
    }

#define VMC_STEADY()                                                          \
    { if constexpr (NFRAG == 2) { VMC(6); } else { VMC(4); } }

#define TILE(t_, BUF)                                                         \
    {                                                                         \
        const ushort* Ab = &As[BUF][0];                                       \
        const ushort* Bb = &Bs[BUF][0];                                       \
        /* phase 1: A0,B0 -> Q(0,0) */                                        \
        RD_A(0); RD_B(0);                                                     \
        ISSUE_HALF(4 * (t_) + 7);                                             \
        LGKM(8);                                                              \
        SBAR(); LGKM(0); SCHED0();                                            \
        PRIO(1); MMQ(0, 0); PRIO(0);                                          \
        SBAR();                                                               \
        /* phase 2: B1 -> Q(0,1) */                                           \
        RD_B(1);                                                              \
        ISSUE_HALF(4 * (t_) + 8);                                             \
        SBAR(); LGKM(0); SCHED0();                                            \
        PRIO(1); MMQ(0, 1); PRIO(0);                                          \
        SBAR();                                                               \
        /* phase 3: A1 -> Q(1,0) */                                           \
        RD_A(1);                                                              \
        ISSUE_HALF(4 * (t_) + 9);                                             \
        SBAR(); LGKM(0); SCHED0();                                            \
        PRIO(1); MMQ(1, 0); PRIO(0);                                          \
        SBAR();                                                               \
        /* phase 4: Q(1,1) + tile-boundary counted vmcnt */                   \
        ISSUE_HALF(4 * (t_) + 10);                                            \
        SBAR(); SCHED0();                                                     \
        PRIO(1); MMQ(1, 1); PRIO(0);                                          \
        if ((t_) + 2 < NT)        { VMC_STEADY(); }                           \
        else if ((t_) + 2 == NT)  { VMC(0); }                                 \
        SBAR();                                                               \
    }

template <int EPI, int NFRAG>
__global__ __launch_bounds__(512, 2) void gemm_nt_8ph(
        const ushort* __restrict__ Aptr, const ushort* __restrict__ Bptr,
        const float* __restrict__ X, float* __restrict__ OUT,
        ushort* __restrict__ Qb_, ushort* __restrict__ Kb_,
        ushort* __restrict__ Vb_, const float2* __restrict__ Tab,
        int M, int N, int K) {
    __shared__ __align__(16) ushort As[2][256 * 64];
    __shared__ __align__(16) ushort Bs[2][NFRAG * 128 * 64];

    // XCD-aware swizzle: XCD k owns a contiguous chunk of tile space.
    int nwg = (int)(gridDim.x * gridDim.y);
    int lin = (int)(blockIdx.y * gridDim.x + blockIdx.x);
    int swz = lin;
    if ((nwg & 7) == 0) swz = (lin & 7) * (nwg >> 3) + (lin >> 3);
    const int bm = (swz / (int)gridDim.x) * 256;
    const int bn = (swz % (int)gridDim.x) * (128 * NFRAG);

    const int w = threadIdx.x >> 6, lane = threadIdx.x & 63;
    const int n = lane & 15, quad = lane >> 4;
    const int wm = w >> 2, wn = w & 3;
    const int an = n & 7;
    const int l8 = lane >> 3;
    const int kb8 = ((lane & 7) ^ l8) * 8;
    const int arow0 = wm * 128 + n;
    const int brow0 = wn * (32 * NFRAG) + n;
    const int NT = K >> 6;

    f32x4 acc[8][2 * NFRAG] = {};
    bf16x8 af[4][2], bfr[2][NFRAG][2];

    // prologue: pre-issue 7 halves (queue order), land first 4, barrier
    ISSUE_HALF(0); ISSUE_HALF(1); ISSUE_HALF(2); ISSUE_HALF(3);
    ISSUE_HALF(4); ISSUE_HALF(5); ISSUE_HALF(6);
    VMC_STEADY();
    SBAR();

    for (int tt = 0; tt < NT; tt += 2) {
        TILE(tt, 0);
        TILE(tt + 1, 1);
    }

    if constexpr (EPI == 2) {
        // ---- fused RoPE + pack epilogue (NFRAG==2 only) ----
        const int bq = bm >> 11;           // batch (BM=256 divides 2048)
        const int s0 = bm & 2047;          // first seq pos of this block
        int col0 = bn + wn * 64;           // wave's head base (one full head)
        int slb = wm * 128 + quad * 4;
        if (col0 < CQ + CK) {
            bool isQ = col0 < CQ;
            ushort* base;
            if (isQ) {
                int head = col0 >> 6;
                base = Qb_ + ((size_t)((bq * 8 + (head >> 2)) * 4 + (head & 3))
                              * SEQ) * 64;
            } else {
                int kh = (col0 - CQ) >> 6;
                base = Kb_ + ((size_t)(bq * 8 + kh) * SEQ) * 64;
            }
            const float QS = 0.18033688011112042f;   // 0.125 * log2(e)
#pragma unroll
            for (int mi = 0; mi < 8; mi++)
#pragma unroll
                for (int r = 0; r < 4; r++) {
                    int s = s0 + slb + mi * 16 + r;
                    float2 t0 = Tab[(size_t)s * 32 + n];
                    float2 t1 = Tab[(size_t)s * 32 + n + 16];
                    float o1a = acc[mi][0][r] * t0.x - acc[mi][2][r] * t0.y;
                    float o2a = acc[mi][2][r] * t0.x + acc[mi][0][r] * t0.y;
                    float o1b = acc[mi][1][r] * t1.x - acc[mi][3][r] * t1.y;
                    float o2b = acc[mi][3][r] * t1.x + acc[mi][1][r] * t1.y;
                    if (isQ) { o1a *= QS; o2a *= QS; o1b *= QS; o2b *= QS; }
                    uint* drow = (uint*)(base + (size_t)s * 64);
                    drow[n]      = cvt_pk_bf16(o1a, o2a);   // cols (n, n+32)
                    drow[16 + n] = cvt_pk_bf16(o1b, o2b);   // cols (n+16, n+48)
                }
        } else {
            int vh = (col0 - CQ - CK) >> 6;
            ushort* vb = Vb_ + (size_t)(bq * 8 + vh) * 64 * SEQ;
#pragma unroll
            for (int mi = 0; mi < 8; mi++)
#pragma unroll
                for (int ni = 0; ni < 2 * NFRAG; ni++) {
                    int d = ni * 16 + n;
                    int s = s0 + slb + mi * 16;
                    uint* dst = (uint*)(vb + (size_t)d * SEQ + s);
                    dst[0] = cvt_pk_bf16(acc[mi][ni][0], acc[mi][ni][1]);
                    dst[1] = cvt_pk_bf16(acc[mi][ni][2], acc[mi][ni][3]);
                }
        }
    } else {
        // EPI == 3: operand-swapped residual epilogue.
        // acc rows  = out-columns c = bm + wm*128 + mi*16 + quad*4 + r
        // acc cols  = tokens      t = bn + wn*(32*NFRAG) + ni*16 + n
#pragma unroll
        for (int mi = 0; mi < 8; mi++)
#pragma unroll
            for (int ni = 0; ni < 2 * NFRAG; ni++) {
                int c0 = bm + wm * 128 + mi * 16 + quad * 4;
                int t  = bn + wn * (32 * NFRAG) + ni * 16 + n;
                const float4 xv = *(const float4*)(X + (size_t)t * DMODEL + c0);
                float4 ov;
                ov.x = xv.x + acc[mi][ni][0];
                ov.y = xv.y + acc[mi][ni][1];
                ov.z = xv.z + acc[mi][ni][2];
                ov.w = xv.w + acc[mi][ni][3];
                *(float4*)(OUT + (size_t)t * DMODEL + c0) = ov;
            }
    }
}

// ---------------- MFMA flash attention, v4 -------------------------------
// Block = (b,g,h, 128-query tile); 8 waves x 16 query rows each.
// No-max exp2 softmax (Q pre-scaled): p = v_exp(S2), l = ones-column MFMA.
// S^T via operand swap -> consecutive keys in-lane -> packed-dword P writes.
// K/V staged by direct global_load_lds, double-buffered, counted vmcnt(2).
// Conflict-free reads via XOR on the GLOBAL source (both-sides-or-neither).
// P per-wave LDS: dwords ((key>>3)*17 + q)*4 + ((key&7)>>1), q in [0,16).
// NOTE: Q and K arrive in the gemm-in epilogue's paired-column layout;
// since both share it, QK^T over d is unchanged.
#define AISSUE(kt_, buf_)                                                     \
    {                                                                         \
        const ushort* Kg_ = Kg0 + (kt_) * 64 * 64;                            \
        const ushort* Vg_ = Vg0 + (kt_) * 64;                                 \
        GLOBAL_TO_LDS16(Kg_ + (w * 8 + l3) * 64 + lx * 8,                     \
                        &Kl[buf_][(size_t)threadIdx.x * 8]);                  \
        GLOBAL_TO_LDS16(Vg_ + (size_t)(w * 8 + l3) * SEQ + lx * 8,            \
                        &Vl[buf_][(size_t)threadIdx.x * 8]);                  \
    }

__global__ __launch_bounds__(512) void attn_mfma_kernel(
        const ushort* __restrict__ Qb, const ushort* __restrict__ Kb,
        const ushort* __restrict__ Vb, ushort* __restrict__ o_bf) {
    __shared__ __align__(16) ushort Kl[2][512 * 8];
    __shared__ __align__(16) ushort Vl[2][512 * 8];
    __shared__ __align__(16) uint   Pl[8][544];

    int blk = blockIdx.x;
    int qt  = 15 - (blk >> 6);          // longest blocks dispatch first
    int bgh = blk & 63;
    int h = bgh & 3, g = (bgh >> 2) & 7, b = bgh >> 5;
    int w = threadIdx.x >> 6, lane = threadIdx.x & 63;
    int n = lane & 15, quad = lane >> 4;
    const int an = n & 7;
    int Q0 = qt * 128;
    int qw = Q0 + w * 16;               // wave's first query row

    // staging lane constants
    const int l3 = lane >> 3;
    const int lx = (lane & 7) ^ l3;

    const ushort* Qh  = Qb + (size_t)((b * 8 + g) * 4 + h) * (SEQ * 64);
    const ushort* Kg0 = Kb + (size_t)(b * 8 + g) * (SEQ * 64);
    const ushort* Vg0 = Vb + (size_t)(b * 8 + g) * (64 * SEQ);

    // Q fragments (rows of Q; per-lane data for B-operand use)
    bf16x8 aq[2];
#pragma unroll
    for (int ks = 0; ks < 2; ks++)
        aq[ks] = *(const bf16x8*)(
            Qh + (size_t)(qw + n) * 64 + ks * 32 + quad * 8);

    f32x4 od[4] = {};
    f32x4 od4 = {};

    short onev = (n == 0) ? (short)0x3F80 : (short)0;
    bf16x8 bones = {onev, onev, onev, onev, onev, onev, onev, onev};

    uint* Pw = Pl[w];
    int nkt = qt * 2 + 2;

    // prologue: tiles 0 and 1 in flight (2 loads each per lane)
    AISSUE(0, 0);
    AISSUE(1, 1);

    for (int kt = 0; kt < nkt; kt++) {
        int buf = kt & 1;
        if (kt + 1 < nkt) { VMC(2); } else { VMC(0); }
        SBAR(); SCHED0();                // buf[kt&1] fully loaded, all waves

        bool act = (kt * 64 <= qw + 15);   // do this wave's rows see kt?
        if (act) {
            const ushort* Kb_ = Kl[buf];
            const ushort* Vb_ = Vl[buf];

            // S^T = K Q^T (operand swap), exp2, cvt_pk, P write
#pragma unroll
            for (int t16k = 0; t16k < 4; t16k++) {
                int krow = (t16k * 16 + n) * 8;
                bf16x8 kf0 = *(const bf16x8*)(Kb_ + (krow + (quad ^ an)) * 8);
                bf16x8 kf1 = *(const bf16x8*)(Kb_ + (krow + ((quad + 4) ^ an)) * 8);
                int key0 = kt * 64 + t16k * 16 + quad * 4;
                f32x4 c = {};
                PRIO(1);
                c = __builtin_amdgcn_mfma_f32_16x16x32_bf16(kf0, aq[0], c, 0, 0, 0);
                c = __builtin_amdgcn_mfma_f32_16x16x32_bf16(kf1, aq[1], c, 0, 0, 0);
                PRIO(0);
                int qrow = qw + n;
                float p[4];
                if (kt * 64 + 63 > qw) {             // tile may mask
#pragma unroll
                    for (int r = 0; r < 4; r++)
                        p[r] = (key0 + r <= qrow) ? __builtin_amdgcn_exp2f(c[r]) : 0.f;
                } else {
#pragma unroll
                    for (int r = 0; r < 4; r++)
                        p[r] = __builtin_amdgcn_exp2f(c[r]);
                }
                uint d0 = cvt_pk_bf16(p[0], p[1]);
                uint d1 = cvt_pk_bf16(p[2], p[3]);
                int base = ((t16k * 2 + (quad >> 1)) * 17 + n) * 4
                           + (quad & 1) * 2;
                Pw[base]     = d0;
                Pw[base + 1] = d1;
            }

            // O += P V   (+ ones column accumulates l)
#pragma unroll
            for (int kb2 = 0; kb2 < 2; kb2++) {
                int kb = kb2 * 4 + quad;
                bf16x8 bv[4];
#pragma unroll
                for (int dt = 0; dt < 4; dt++)
                    bv[dt] = *(const bf16x8*)(Vb_ +
                        (((dt * 16 + n) * 8 + (kb ^ an)) * 8));
                bf16x8 ap = *(const bf16x8*)(
                    (const ushort*)Pw + ((kb2 * 4 + quad) * 17 + n) * 8);
                PRIO(1);
#pragma unroll
                for (int dt = 0; dt < 4; dt++)
                    od[dt] = __builtin_amdgcn_mfma_f32_16x16x32_bf16(
                        ap, bv[dt], od[dt], 0, 0, 0);
                od4 = __builtin_amdgcn_mfma_f32_16x16x32_bf16(
                    ap, bones, od4, 0, 0, 0);
                PRIO(0);
            }
        }

        SCHED0(); SBAR();                // all reads of buf done
        if (kt + 2 < nkt) AISSUE(kt + 2, buf);
    }

    // epilogue: l lives in column 0 of od4 (lane n==0); broadcast, divide
    float linv[4];
#pragma unroll
    for (int r = 0; r < 4; r++) {
        float lv = __shfl(od4[r], lane & 48);
        linv[r] = __builtin_amdgcn_rcpf(lv);
    }
#pragma unroll
    for (int dt = 0; dt < 4; dt++)
#pragma unroll
        for (int r = 0; r < 4; r++) {
            int q = qw + quad * 4 + r;
            int col = (g * 4 + h) * 64 + dt * 16 + n;
            o_bf[(size_t)(b * SEQ + q) * DMODEL + col] =
                f2bf(od[dt][r] * linv[r]);
        }
}

extern "C" void kernel_launch(void* const* d_in, const int* in_sizes, int n_in,
                              void* d_out, int out_size, void* d_ws, size_t ws_size,
                              hipStream_t stream) {
    const float* x     = (const float*)d_in[0];
    const float* w_in  = (const float*)d_in[1];
    const float* w_out = (const float*)d_in[2];
    const float* rms_w = (const float*)d_in[3];
    float* out = (float*)d_out;

    // Workspace layout (76 MB):
    //   [0,16)   Qb bf16      [16,20) Kb     [20,24) Vb
    //   [24,40)  o_bf bf16    (rope_tab f32x2 512KB aliases o_bf head:
    //                          tab live only until gemm-in ends; o_bf
    //                          written first by attention, after gemm-in)
    //   [40,48)  w_out_bf     [48,64) y_bf   [64,76) w_in_bf
    const size_t MB = 1024 * 1024;
    char* ws = (char*)d_ws;
    ushort* Qb       = (ushort*)ws;
    ushort* Kb       = (ushort*)(ws + 16 * MB);
    ushort* Vb       = (ushort*)(ws + 20 * MB);
    ushort* o_bf     = (ushort*)(ws + 24 * MB);
    float2* rope_tab = (float2*)(ws + 24 * MB);
    ushort* w_out_bf = (ushort*)(ws + 40 * MB);
    ushort* y_bf     = (ushort*)(ws + 48 * MB);
    ushort* w_in_bf  = (ushort*)(ws + 64 * MB);

    prep_kernel<<<PREP_TOTAL, 256, 0, stream>>>(
        x, rms_w, w_in, w_out, y_bf, w_in_bf, w_out_bf, rope_tab);

    // GEMM-in with fused RoPE/pack epilogue: writes Qb/Kb/Vb directly.
    gemm_nt_8ph<2, 2><<<dim3(CONCAT / 256, TOKENS / 256), 512, 0, stream>>>(
        y_bf, w_in_bf, nullptr, nullptr, Qb, Kb, Vb, rope_tab,
        TOKENS, CONCAT, DMODEL);

    attn_mfma_kernel<<<1024, 512, 0, stream>>>(Qb, Kb, Vb, o_bf);

    // GEMM-out, operand-swapped: A = w_out (M=DMODEL), B = o_bf (N=TOKENS).
    gemm_nt_8ph<3, 1><<<dim3(TOKENS / 128, DMODEL / 256), 512, 0, stream>>>(
        w_out_bf, o_bf, x, out, nullptr, nullptr, nullptr, nullptr,
        DMODEL, TOKENS, DMODEL);
}

// Round 9
// 271.982 us; speedup vs baseline: 1.0292x; 1.0211x over previous
//
#include <hip/hip_runtime.h>
#include <hip/hip_bf16.h>

// fp32 problem: b=2, s=2048, D=2048, 32 q-heads / 8 kv-groups, d=64
#define TOKENS   4096
#define SEQ      2048
#define DMODEL   2048
#define CONCAT   3072
#define NHEADS   32
#define NGROUPS  8
#define HPERG    4
#define CQ       2048
#define CK       512

typedef __attribute__((ext_vector_type(8))) short bf16x8;
typedef __attribute__((ext_vector_type(4))) float f32x4;

__device__ __forceinline__ ushort f2bf(float f) {
    __hip_bfloat16 h = __float2bfloat16(f);
    return __builtin_bit_cast(ushort, h);
}

// packed f32x2 -> bf16x2 (RNE), dst = bf16(hi)<<16 | bf16(lo)
__device__ __forceinline__ uint cvt_pk_bf16(float lo, float hi) {
    uint r;
    asm("v_cvt_pk_bf16_f32 %0, %1, %2" : "=v"(r) : "v"(lo), "v"(hi));
    return r;
}

#define GLOBAL_TO_LDS16(g, l)                                                  \
    __builtin_amdgcn_global_load_lds(                                          \
        (const __attribute__((address_space(1))) void*)(g),                    \
        (__attribute__((address_space(3))) void*)(l), 16, 0, 0)

// ---------------- prep: rope table + RMSNorm + weight packs (1 launch) ---
#define PREP_ROPE 256
#define PREP_RMS  (PREP_ROPE + TOKENS)
#define N4_WIN  (CONCAT * DMODEL / 4)
#define N4_WOUT (DMODEL * DMODEL / 4)
#define PREP_TOTAL (PREP_RMS + (N4_WIN + N4_WOUT + 255) / 256)

__global__ void prep_kernel(const float* __restrict__ x,
                            const float* __restrict__ rms_w,
                            const float* __restrict__ w_in,
                            const float* __restrict__ w_out,
                            ushort* __restrict__ y_bf,
                            ushort* __restrict__ w_in_bf,
                            ushort* __restrict__ w_out_bf,
                            float2* __restrict__ tab) {
    int blk = blockIdx.x, tid = threadIdx.x;
    if (blk < PREP_ROPE) {
        int i = blk * 256 + tid;                 // 65536 = 2048 * 32
        int s = i >> 5, j = i & 31;
        const float LOG2_THETA = 13.287712379549449f;
        float inv = exp2f(-((float)j / 32.0f) * LOG2_THETA);
        float ang = (float)s * inv;
        tab[i] = make_float2(cosf(ang), sinf(ang));
    } else if (blk < PREP_RMS) {
        int t = blk - PREP_ROPE;
        const float4* xr = (const float4*)(x + (size_t)t * DMODEL);
        float4 v[2];
        float ss = 0.f;
#pragma unroll
        for (int i = 0; i < 2; i++) {
            v[i] = xr[tid + i * 256];
            ss += v[i].x * v[i].x + v[i].y * v[i].y + v[i].z * v[i].z + v[i].w * v[i].w;
        }
#pragma unroll
        for (int off = 32; off >= 1; off >>= 1) ss += __shfl_xor(ss, off);
        __shared__ float red[4];
        int wid = tid >> 6;
        if ((tid & 63) == 0) red[wid] = ss;
        __syncthreads();
        float total = red[0] + red[1] + red[2] + red[3];
        float scale = rsqrtf(total * (1.0f / DMODEL) + 1e-6f);
        const float4* wr = (const float4*)rms_w;
        ushort4* yr = (ushort4*)(y_bf + (size_t)t * DMODEL);
#pragma unroll
        for (int i = 0; i < 2; i++) {
            int c = tid + i * 256;
            float4 wv = wr[c];
            ushort4 o;
            o.x = f2bf(v[i].x * scale * wv.x);
            o.y = f2bf(v[i].y * scale * wv.y);
            o.z = f2bf(v[i].z * scale * wv.z);
            o.w = f2bf(v[i].w * scale * wv.w);
            yr[c] = o;
        }
    } else {
        int i = (blk - PREP_RMS) * 256 + tid;
        const float* src;
        ushort* dst;
        int j;
        if (i < N4_WIN) { src = w_in; dst = w_in_bf; j = i; }
        else if (i < N4_WIN + N4_WOUT) { src = w_out; dst = w_out_bf; j = i - N4_WIN; }
        else return;
        float4 v = ((const float4*)src)[j];
        ushort4 o;
        o.x = f2bf(v.x); o.y = f2bf(v.y); o.z = f2bf(v.z); o.w = f2bf(v.w);
        ((ushort4*)dst)[j] = o;
    }
}

// ---------------- 256xBN 8-phase MFMA GEMM -------------------------------
// C[M,N] = A[M,K] * B[N,K]^T, bf16 in.  BN = 128*NFRAG.
// 512 thr = 8 waves (2M x 4N); wave tile 128 x (32*NFRAG); BK=64.
// Rolling half-tile buffer, raw s_barrier, counted vmcnt.
// NFRAG==2: 4 phases/tile, 16 MFMA each, steady vmcnt(6).
// NFRAG==1: 2 phases/tile, 16 MFMA each (phase A: Q00+Q01, phase B:
//   Q10+Q11) -- halves barrier count for the thin-tile case; steady
//   vmcnt(3) (covers through A1(t+1): younger = A0(t+2)x2 + B0(t+2)x1).
// LDS swizzle: linear dest + pre-swizzled global src.
// T1: XCD-aware block swizzle (nwg%8==0 for both call sites -> bijective).
// EPI=2 (NFRAG=2, gemm-in): fused RoPE+bf16 pack from acc into Qb/Kb/Vb
//   (paired-column Q/K layout; both share the d-permutation so QK^T is
//   invariant; attention kernel unchanged).
// EPI=3 (NFRAG=1, gemm-out, operands swapped: A=w_out, B=o_bf):
//   lane's 4 acc rows = 4 consecutive out-columns at one token ->
//   float4 residual load + float4 store.
#define LGKM(nn) asm volatile("s_waitcnt lgkmcnt(" #nn ")" ::: "memory")
#define VMC(nn)  asm volatile("s_waitcnt vmcnt(" #nn ")" ::: "memory")
#define SBAR()   __builtin_amdgcn_s_barrier()
#define SCHED0() __builtin_amdgcn_sched_barrier(0)
#define PRIO(p)  __builtin_amdgcn_s_setprio(p)

#define RD_A(mh)                                                              \
    _Pragma("unroll") for (int mi = 0; mi < 4; mi++)                          \
    _Pragma("unroll") for (int ks = 0; ks < 2; ks++)                          \
        af[mi][ks] = *(const bf16x8*)(Ab +                                    \
            ((arow0 + (mh) * 64 + mi * 16) * 8 +                              \
             ((ks * 4 + quad) ^ an)) * 8);

#define RD_B(nh)                                                              \
    _Pragma("unroll") for (int ni = 0; ni < NFRAG; ni++)                      \
    _Pragma("unroll") for (int ks = 0; ks < 2; ks++)                          \
        bfr[nh][ni][ks] = *(const bf16x8*)(Bb +                               \
            ((brow0 + (nh) * (16 * NFRAG) + ni * 16) * 8 +                    \
             ((ks * 4 + quad) ^ an)) * 8);

#define MMQ(mh, nh)                                                           \
    _Pragma("unroll") for (int mi = 0; mi < 4; mi++)                          \
    _Pragma("unroll") for (int ni = 0; ni < NFRAG; ni++)                      \
    _Pragma("unroll") for (int ks = 0; ks < 2; ks++)                          \
        acc[(mh) * 4 + mi][(nh) * NFRAG + ni] =                               \
            __builtin_amdgcn_mfma_f32_16x16x32_bf16(af[mi][ks],               \
                bfr[nh][ni][ks], acc[(mh) * 4 + mi][(nh) * NFRAG + ni],       \
                0, 0, 0);

#define ISSUE_HALF(H_)                                                        \
    {                                                                         \
        int H = (H_);                                                         \
        if (H < 4 * NT) {                                                     \
            int t2 = H >> 2, j2 = H & 3;                                      \
            int k0 = t2 << 6;                                                 \
            if (j2 == 0 || j2 == 3) {                                         \
                int half = (j2 == 3);                                         \
                ushort* lb = (ushort*)&As[t2 & 1][0];                         \
                _Pragma("unroll") for (int c = 0; c < 2; c++) {               \
                    int s = w * 2 + c;                                        \
                    int row = (s >> 3) * 128 + half * 64 + (s & 7) * 8;       \
                    const ushort* g = Aptr +                                  \
                        (size_t)(bm + row + l8) * K + k0 + kb8;               \
                    GLOBAL_TO_LDS16(g, lb + row * 64);                        \
                }                                                             \
            } else {                                                          \
                int half = (j2 == 2);                                         \
                ushort* lb = (ushort*)&Bs[t2 & 1][0];                         \
                if constexpr (NFRAG == 2) {                                   \
                    _Pragma("unroll") for (int c = 0; c < 2; c++) {           \
                        int s = w * 2 + c;                                    \
                        int row = (s >> 2) * 64 + half * 32 + (s & 3) * 8;    \
                        const ushort* g = Bptr +                              \
                            (size_t)(bn + row + l8) * K + k0 + kb8;           \
                        GLOBAL_TO_LDS16(g, lb + row * 64);                    \
                    }                                                         \
                } else {                                                      \
                    int row = (w >> 1) * 32 + half * 16 + (w & 1) * 8;        \
                    const ushort* g = Bptr +                                  \
                        (size_t)(bn + row + l8) * K + k0 + kb8;               \
                    GLOBAL_TO_LDS16(g, lb + row * 64);                        \
                }                                                             \
            }                                                                 \
        }                                                                     \
    }

#define TILE(t_, BUF)                                                         \
    {                                                                         \
        const ushort* Ab = &As[BUF][0];                                       \
        const ushort* Bb = &Bs[BUF][0];                                       \
        /* phase 1: A0,B0 -> Q(0,0) */                                        \
        RD_A(0); RD_B(0);                                                     \
        ISSUE_HALF(4 * (t_) + 7);                                             \
        LGKM(8);                                                              \
        SBAR(); LGKM(0); SCHED0();                                            \
        PRIO(1); MMQ(0, 0); PRIO(0);                                          \
        SBAR();                                                               \
        /* phase 2: B1 -> Q(0,1) */                                           \
        RD_B(1);                                                              \
        ISSUE_HALF(4 * (t_) + 8);                                             \
        SBAR(); LGKM(0); SCHED0();                                            \
        PRIO(1); MMQ(0, 1); PRIO(0);                                          \
        SBAR();                                                               \
        /* phase 3: A1 -> Q(1,0) */                                           \
        RD_A(1);                                                              \
        ISSUE_HALF(4 * (t_) + 9);                                             \
        SBAR(); LGKM(0); SCHED0();                                            \
        PRIO(1); MMQ(1, 0); PRIO(0);                                          \
        SBAR();                                                               \
        /* phase 4: Q(1,1) + tile-boundary counted vmcnt */                   \
        ISSUE_HALF(4 * (t_) + 10);                                            \
        SBAR(); SCHED0();                                                     \
        PRIO(1); MMQ(1, 1); PRIO(0);                                          \
        if ((t_) + 2 < NT)        { VMC(6); }                                 \
        else if ((t_) + 2 == NT)  { VMC(0); }                                 \
        SBAR();                                                               \
    }

// 2-phase tile for NFRAG==1 (16 MFMA per phase, 4 barriers/tile).
// Hazards: phase A issues halves 4t+6,4t+7 -> buffers (t+1)&1 (opposite);
// phase B issues 4t+8 (A0(t+2) rows {0-63,128-191}) and 4t+9 (B0(t+2)
// half-0 rows) into buf t&1 -- disjoint from phase B's A1 reads (rows
// {64-127,192-255}), and Bs reads completed before phase A's end barrier.
#define TILE2(t_, BUF)                                                        \
    {                                                                         \
        const ushort* Ab = &As[BUF][0];                                       \
        const ushort* Bb = &Bs[BUF][0];                                       \
        /* phase A: A0,B0,B1 -> Q(0,0)+Q(0,1) */                              \
        RD_A(0); RD_B(0); RD_B(1);                                            \
        ISSUE_HALF(4 * (t_) + 6);                                             \
        ISSUE_HALF(4 * (t_) + 7);                                             \
        LGKM(8);                                                              \
        SBAR(); LGKM(0); SCHED0();                                            \
        PRIO(1); MMQ(0, 0); MMQ(0, 1); PRIO(0);                               \
        SBAR();                                                               \
        /* phase B: A1 -> Q(1,0)+Q(1,1) + tile-boundary counted vmcnt */      \
        RD_A(1);                                                              \
        ISSUE_HALF(4 * (t_) + 8);                                             \
        ISSUE_HALF(4 * (t_) + 9);                                             \
        SBAR(); LGKM(0); SCHED0();                                            \
        PRIO(1); MMQ(1, 0); MMQ(1, 1); PRIO(0);                               \
        if ((t_) + 2 < NT)        { VMC(3); }                                 \
        else if ((t_) + 2 == NT)  { VMC(0); }                                 \
        SBAR();                                                               \
    }

template <int EPI, int NFRAG>
__global__ __launch_bounds__(512, 2) void gemm_nt_8ph(
        const ushort* __restrict__ Aptr, const ushort* __restrict__ Bptr,
        const float* __restrict__ X, float* __restrict__ OUT,
        ushort* __restrict__ Qb_, ushort* __restrict__ Kb_,
        ushort* __restrict__ Vb_, const float2* __restrict__ Tab,
        int M, int N, int K) {
    __shared__ __align__(16) ushort As[2][256 * 64];
    __shared__ __align__(16) ushort Bs[2][NFRAG * 128 * 64];

    // XCD-aware swizzle: XCD k owns a contiguous chunk of tile space.
    int nwg = (int)(gridDim.x * gridDim.y);
    int lin = (int)(blockIdx.y * gridDim.x + blockIdx.x);
    int swz = lin;
    if ((nwg & 7) == 0) swz = (lin & 7) * (nwg >> 3) + (lin >> 3);
    const int bm = (swz / (int)gridDim.x) * 256;
    const int bn = (swz % (int)gridDim.x) * (128 * NFRAG);

    const int w = threadIdx.x >> 6, lane = threadIdx.x & 63;
    const int n = lane & 15, quad = lane >> 4;
    const int wm = w >> 2, wn = w & 3;
    const int an = n & 7;
    const int l8 = lane >> 3;
    const int kb8 = ((lane & 7) ^ l8) * 8;
    const int arow0 = wm * 128 + n;
    const int brow0 = wn * (32 * NFRAG) + n;
    const int NT = K >> 6;

    f32x4 acc[8][2 * NFRAG] = {};
    bf16x8 af[4][2], bfr[2][NFRAG][2];

    if constexpr (NFRAG == 1) {
        // 2-phase prologue: halves 0..5; wait so halves 0..3 (tile 0) land.
        ISSUE_HALF(0); ISSUE_HALF(1); ISSUE_HALF(2);
        ISSUE_HALF(3); ISSUE_HALF(4); ISSUE_HALF(5);
        VMC(3);
        SBAR();
        for (int tt = 0; tt < NT; tt += 2) {
            TILE2(tt, 0);
            TILE2(tt + 1, 1);
        }
    } else {
        // 4-phase prologue: halves 0..6; land first 4.
        ISSUE_HALF(0); ISSUE_HALF(1); ISSUE_HALF(2); ISSUE_HALF(3);
        ISSUE_HALF(4); ISSUE_HALF(5); ISSUE_HALF(6);
        VMC(6);
        SBAR();
        for (int tt = 0; tt < NT; tt += 2) {
            TILE(tt, 0);
            TILE(tt + 1, 1);
        }
    }

    if constexpr (EPI == 2) {
        // ---- fused RoPE + pack epilogue (NFRAG==2 only) ----
        const int bq = bm >> 11;           // batch (BM=256 divides 2048)
        const int s0 = bm & 2047;          // first seq pos of this block
        int col0 = bn + wn * 64;           // wave's head base (one full head)
        int slb = wm * 128 + quad * 4;
        if (col0 < CQ + CK) {
            bool isQ = col0 < CQ;
            ushort* base;
            if (isQ) {
                int head = col0 >> 6;
                base = Qb_ + ((size_t)((bq * 8 + (head >> 2)) * 4 + (head & 3))
                              * SEQ) * 64;
            } else {
                int kh = (col0 - CQ) >> 6;
                base = Kb_ + ((size_t)(bq * 8 + kh) * SEQ) * 64;
            }
            const float QS = 0.18033688011112042f;   // 0.125 * log2(e)
#pragma unroll
            for (int mi = 0; mi < 8; mi++)
#pragma unroll
                for (int r = 0; r < 4; r++) {
                    int s = s0 + slb + mi * 16 + r;
                    float2 t0 = Tab[(size_t)s * 32 + n];
                    float2 t1 = Tab[(size_t)s * 32 + n + 16];
                    float o1a = acc[mi][0][r] * t0.x - acc[mi][2][r] * t0.y;
                    float o2a = acc[mi][2][r] * t0.x + acc[mi][0][r] * t0.y;
                    float o1b = acc[mi][1][r] * t1.x - acc[mi][3][r] * t1.y;
                    float o2b = acc[mi][3][r] * t1.x + acc[mi][1][r] * t1.y;
                    if (isQ) { o1a *= QS; o2a *= QS; o1b *= QS; o2b *= QS; }
                    uint* drow = (uint*)(base + (size_t)s * 64);
                    drow[n]      = cvt_pk_bf16(o1a, o2a);   // cols (n, n+32)
                    drow[16 + n] = cvt_pk_bf16(o1b, o2b);   // cols (n+16, n+48)
                }
        } else {
            int vh = (col0 - CQ - CK) >> 6;
            ushort* vb = Vb_ + (size_t)(bq * 8 + vh) * 64 * SEQ;
#pragma unroll
            for (int mi = 0; mi < 8; mi++)
#pragma unroll
                for (int ni = 0; ni < 2 * NFRAG; ni++) {
                    int d = ni * 16 + n;
                    int s = s0 + slb + mi * 16;
                    uint* dst = (uint*)(vb + (size_t)d * SEQ + s);
                    dst[0] = cvt_pk_bf16(acc[mi][ni][0], acc[mi][ni][1]);
                    dst[1] = cvt_pk_bf16(acc[mi][ni][2], acc[mi][ni][3]);
                }
        }
    } else {
        // EPI == 3: operand-swapped residual epilogue.
        // acc rows  = out-columns c = bm + wm*128 + mi*16 + quad*4 + r
        // acc cols  = tokens      t = bn + wn*(32*NFRAG) + ni*16 + n
#pragma unroll
        for (int mi = 0; mi < 8; mi++)
#pragma unroll
            for (int ni = 0; ni < 2 * NFRAG; ni++) {
                int c0 = bm + wm * 128 + mi * 16 + quad * 4;
                int t  = bn + wn * (32 * NFRAG) + ni * 16 + n;
                const float4 xv = *(const float4*)(X + (size_t)t * DMODEL + c0);
                float4 ov;
                ov.x = xv.x + acc[mi][ni][0];
                ov.y = xv.y + acc[mi][ni][1];
                ov.z = xv.z + acc[mi][ni][2];
                ov.w = xv.w + acc[mi][ni][3];
                *(float4*)(OUT + (size_t)t * DMODEL + c0) = ov;
            }
    }
}

// ---------------- MFMA flash attention, v4 -------------------------------
// Block = (b,g,h, 128-query tile); 8 waves x 16 query rows each.
// No-max exp2 softmax (Q pre-scaled): p = v_exp(S2), l = ones-column MFMA.
// S^T via operand swap -> consecutive keys in-lane -> packed-dword P writes.
// K/V staged by direct global_load_lds, double-buffered, counted vmcnt(2).
// Conflict-free reads via XOR on the GLOBAL source (both-sides-or-neither).
// P per-wave LDS: dwords ((key>>3)*17 + q)*4 + ((key&7)>>1), q in [0,16).
// NOTE: Q and K arrive in the gemm-in epilogue's paired-column layout;
// since both share it, QK^T over d is unchanged.
#define AISSUE(kt_, buf_)                                                     \
    {                                                                         \
        const ushort* Kg_ = Kg0 + (kt_) * 64 * 64;                            \
        const ushort* Vg_ = Vg0 + (kt_) * 64;                                 \
        GLOBAL_TO_LDS16(Kg_ + (w * 8 + l3) * 64 + lx * 8,                     \
                        &Kl[buf_][(size_t)threadIdx.x * 8]);                  \
        GLOBAL_TO_LDS16(Vg_ + (size_t)(w * 8 + l3) * SEQ + lx * 8,            \
                        &Vl[buf_][(size_t)threadIdx.x * 8]);                  \
    }

__global__ __launch_bounds__(512) void attn_mfma_kernel(
        const ushort* __restrict__ Qb, const ushort* __restrict__ Kb,
        const ushort* __restrict__ Vb, ushort* __restrict__ o_bf) {
    __shared__ __align__(16) ushort Kl[2][512 * 8];
    __shared__ __align__(16) ushort Vl[2][512 * 8];
    __shared__ __align__(16) uint   Pl[8][544];

    int blk = blockIdx.x;
    int qt  = 15 - (blk >> 6);          // longest blocks dispatch first
    int bgh = blk & 63;
    int h = bgh & 3, g = (bgh >> 2) & 7, b = bgh >> 5;
    int w = threadIdx.x >> 6, lane = threadIdx.x & 63;
    int n = lane & 15, quad = lane >> 4;
    const int an = n & 7;
    int Q0 = qt * 128;
    int qw = Q0 + w * 16;               // wave's first query row

    // staging lane constants
    const int l3 = lane >> 3;
    const int lx = (lane & 7) ^ l3;

    const ushort* Qh  = Qb + (size_t)((b * 8 + g) * 4 + h) * (SEQ * 64);
    const ushort* Kg0 = Kb + (size_t)(b * 8 + g) * (SEQ * 64);
    const ushort* Vg0 = Vb + (size_t)(b * 8 + g) * (64 * SEQ);

    // Q fragments (rows of Q; per-lane data for B-operand use)
    bf16x8 aq[2];
#pragma unroll
    for (int ks = 0; ks < 2; ks++)
        aq[ks] = *(const bf16x8*)(
            Qh + (size_t)(qw + n) * 64 + ks * 32 + quad * 8);

    f32x4 od[4] = {};
    f32x4 od4 = {};

    short onev = (n == 0) ? (short)0x3F80 : (short)0;
    bf16x8 bones = {onev, onev, onev, onev, onev, onev, onev, onev};

    uint* Pw = Pl[w];
    int nkt = qt * 2 + 2;

    // prologue: tiles 0 and 1 in flight (2 loads each per lane)
    AISSUE(0, 0);
    AISSUE(1, 1);

    for (int kt = 0; kt < nkt; kt++) {
        int buf = kt & 1;
        if (kt + 1 < nkt) { VMC(2); } else { VMC(0); }
        SBAR(); SCHED0();                // buf[kt&1] fully loaded, all waves

        bool act = (kt * 64 <= qw + 15);   // do this wave's rows see kt?
        if (act) {
            const ushort* Kb_ = Kl[buf];
            const ushort* Vb_ = Vl[buf];

            // S^T = K Q^T (operand swap), exp2, cvt_pk, P write
#pragma unroll
            for (int t16k = 0; t16k < 4; t16k++) {
                int krow = (t16k * 16 + n) * 8;
                bf16x8 kf0 = *(const bf16x8*)(Kb_ + (krow + (quad ^ an)) * 8);
                bf16x8 kf1 = *(const bf16x8*)(Kb_ + (krow + ((quad + 4) ^ an)) * 8);
                int key0 = kt * 64 + t16k * 16 + quad * 4;
                f32x4 c = {};
                PRIO(1);
                c = __builtin_amdgcn_mfma_f32_16x16x32_bf16(kf0, aq[0], c, 0, 0, 0);
                c = __builtin_amdgcn_mfma_f32_16x16x32_bf16(kf1, aq[1], c, 0, 0, 0);
                PRIO(0);
                int qrow = qw + n;
                float p[4];
                if (kt * 64 + 63 > qw) {             // tile may mask
#pragma unroll
                    for (int r = 0; r < 4; r++)
                        p[r] = (key0 + r <= qrow) ? __builtin_amdgcn_exp2f(c[r]) : 0.f;
                } else {
#pragma unroll
                    for (int r = 0; r < 4; r++)
                        p[r] = __builtin_amdgcn_exp2f(c[r]);
                }
                uint d0 = cvt_pk_bf16(p[0], p[1]);
                uint d1 = cvt_pk_bf16(p[2], p[3]);
                int base = ((t16k * 2 + (quad >> 1)) * 17 + n) * 4
                           + (quad & 1) * 2;
                Pw[base]     = d0;
                Pw[base + 1] = d1;
            }

            // O += P V   (+ ones column accumulates l)
#pragma unroll
            for (int kb2 = 0; kb2 < 2; kb2++) {
                int kb = kb2 * 4 + quad;
                bf16x8 bv[4];
#pragma unroll
                for (int dt = 0; dt < 4; dt++)
                    bv[dt] = *(const bf16x8*)(Vb_ +
                        (((dt * 16 + n) * 8 + (kb ^ an)) * 8));
                bf16x8 ap = *(const bf16x8*)(
                    (const ushort*)Pw + ((kb2 * 4 + quad) * 17 + n) * 8);
                PRIO(1);
#pragma unroll
                for (int dt = 0; dt < 4; dt++)
                    od[dt] = __builtin_amdgcn_mfma_f32_16x16x32_bf16(
                        ap, bv[dt], od[dt], 0, 0, 0);
                od4 = __builtin_amdgcn_mfma_f32_16x16x32_bf16(
                    ap, bones, od4, 0, 0, 0);
                PRIO(0);
            }
        }

        SCHED0(); SBAR();                // all reads of buf done
        if (kt + 2 < nkt) AISSUE(kt + 2, buf);
    }

    // epilogue: l lives in column 0 of od4 (lane n==0); broadcast, divide
    float linv[4];
#pragma unroll
    for (int r = 0; r < 4; r++) {
        float lv = __shfl(od4[r], lane & 48);
        linv[r] = __builtin_amdgcn_rcpf(lv);
    }
#pragma unroll
    for (int dt = 0; dt < 4; dt++)
#pragma unroll
        for (int r = 0; r < 4; r++) {
            int q = qw + quad * 4 + r;
            int col = (g * 4 + h) * 64 + dt * 16 + n;
            o_bf[(size_t)(b * SEQ + q) * DMODEL + col] =
                f2bf(od[dt][r] * linv[r]);
        }
}

extern "C" void kernel_launch(void* const* d_in, const int* in_sizes, int n_in,
                              void* d_out, int out_size, void* d_ws, size_t ws_size,
                              hipStream_t stream) {
    const float* x     = (const float*)d_in[0];
    const float* w_in  = (const float*)d_in[1];
    const float* w_out = (const float*)d_in[2];
    const float* rms_w = (const float*)d_in[3];
    float* out = (float*)d_out;

    // Workspace layout (76 MB):
    //   [0,16)   Qb bf16      [16,20) Kb     [20,24) Vb
    //   [24,40)  o_bf bf16    (rope_tab f32x2 512KB aliases o_bf head:
    //                          tab live only until gemm-in ends; o_bf
    //                          written first by attention, after gemm-in)
    //   [40,48)  w_out_bf     [48,64) y_bf   [64,76) w_in_bf
    const size_t MB = 1024 * 1024;
    char* ws = (char*)d_ws;
    ushort* Qb       = (ushort*)ws;
    ushort* Kb       = (ushort*)(ws + 16 * MB);
    ushort* Vb       = (ushort*)(ws + 20 * MB);
    ushort* o_bf     = (ushort*)(ws + 24 * MB);
    float2* rope_tab = (float2*)(ws + 24 * MB);
    ushort* w_out_bf = (ushort*)(ws + 40 * MB);
    ushort* y_bf     = (ushort*)(ws + 48 * MB);
    ushort* w_in_bf  = (ushort*)(ws + 64 * MB);

    prep_kernel<<<PREP_TOTAL, 256, 0, stream>>>(
        x, rms_w, w_in, w_out, y_bf, w_in_bf, w_out_bf, rope_tab);

    // GEMM-in with fused RoPE/pack epilogue: writes Qb/Kb/Vb directly.
    gemm_nt_8ph<2, 2><<<dim3(CONCAT / 256, TOKENS / 256), 512, 0, stream>>>(
        y_bf, w_in_bf, nullptr, nullptr, Qb, Kb, Vb, rope_tab,
        TOKENS, CONCAT, DMODEL);

    attn_mfma_kernel<<<1024, 512, 0, stream>>>(Qb, Kb, Vb, o_bf);

    // GEMM-out, operand-swapped: A = w_out (M=DMODEL), B = o_bf (N=TOKENS).
    gemm_nt_8ph<3, 1><<<dim3(TOKENS / 128, DMODEL / 256), 512, 0, stream>>>(
        w_out_bf, o_bf, x, out, nullptr, nullptr, nullptr, nullptr,
        DMODEL, TOKENS, DMODEL);
}

// Round 10
// 262.447 us; speedup vs baseline: 1.0666x; 1.0363x over previous
//
#include <hip/hip_runtime.h>
#include <hip/hip_bf16.h>

// fp32 problem: b=2, s=2048, D=2048, 32 q-heads / 8 kv-groups, d=64
#define TOKENS   4096
#define SEQ      2048
#define DMODEL   2048
#define CONCAT   3072
#define NHEADS   32
#define NGROUPS  8
#define HPERG    4
#define CQ       2048
#define CK       512

typedef __attribute__((ext_vector_type(8))) short bf16x8;
typedef __attribute__((ext_vector_type(4))) float f32x4;

__device__ __forceinline__ ushort f2bf(float f) {
    __hip_bfloat16 h = __float2bfloat16(f);
    return __builtin_bit_cast(ushort, h);
}

// packed f32x2 -> bf16x2 (RNE), dst = bf16(hi)<<16 | bf16(lo)
__device__ __forceinline__ uint cvt_pk_bf16(float lo, float hi) {
    uint r;
    asm("v_cvt_pk_bf16_f32 %0, %1, %2" : "=v"(r) : "v"(lo), "v"(hi));
    return r;
}

#define GLOBAL_TO_LDS16(g, l)                                                  \
    __builtin_amdgcn_global_load_lds(                                          \
        (const __attribute__((address_space(1))) void*)(g),                    \
        (__attribute__((address_space(3))) void*)(l), 16, 0, 0)

// ---------------- prep: rope table + RMSNorm + weight packs (1 launch) ---
#define PREP_ROPE 256
#define PREP_RMS  (PREP_ROPE + TOKENS)
#define N4_WIN  (CONCAT * DMODEL / 4)
#define N4_WOUT (DMODEL * DMODEL / 4)
#define PREP_TOTAL (PREP_RMS + (N4_WIN + N4_WOUT + 255) / 256)

__global__ void prep_kernel(const float* __restrict__ x,
                            const float* __restrict__ rms_w,
                            const float* __restrict__ w_in,
                            const float* __restrict__ w_out,
                            ushort* __restrict__ y_bf,
                            ushort* __restrict__ w_in_bf,
                            ushort* __restrict__ w_out_bf,
                            float2* __restrict__ tab) {
    int blk = blockIdx.x, tid = threadIdx.x;
    if (blk < PREP_ROPE) {
        int i = blk * 256 + tid;                 // 65536 = 2048 * 32
        int s = i >> 5, j = i & 31;
        const float LOG2_THETA = 13.287712379549449f;
        float inv = exp2f(-((float)j / 32.0f) * LOG2_THETA);
        float ang = (float)s * inv;
        tab[i] = make_float2(cosf(ang), sinf(ang));
    } else if (blk < PREP_RMS) {
        int t = blk - PREP_ROPE;
        const float4* xr = (const float4*)(x + (size_t)t * DMODEL);
        float4 v[2];
        float ss = 0.f;
#pragma unroll
        for (int i = 0; i < 2; i++) {
            v[i] = xr[tid + i * 256];
            ss += v[i].x * v[i].x + v[i].y * v[i].y + v[i].z * v[i].z + v[i].w * v[i].w;
        }
#pragma unroll
        for (int off = 32; off >= 1; off >>= 1) ss += __shfl_xor(ss, off);
        __shared__ float red[4];
        int wid = tid >> 6;
        if ((tid & 63) == 0) red[wid] = ss;
        __syncthreads();
        float total = red[0] + red[1] + red[2] + red[3];
        float scale = rsqrtf(total * (1.0f / DMODEL) + 1e-6f);
        const float4* wr = (const float4*)rms_w;
        ushort4* yr = (ushort4*)(y_bf + (size_t)t * DMODEL);
#pragma unroll
        for (int i = 0; i < 2; i++) {
            int c = tid + i * 256;
            float4 wv = wr[c];
            ushort4 o;
            o.x = f2bf(v[i].x * scale * wv.x);
            o.y = f2bf(v[i].y * scale * wv.y);
            o.z = f2bf(v[i].z * scale * wv.z);
            o.w = f2bf(v[i].w * scale * wv.w);
            yr[c] = o;
        }
    } else {
        int i = (blk - PREP_RMS) * 256 + tid;
        const float* src;
        ushort* dst;
        int j;
        if (i < N4_WIN) { src = w_in; dst = w_in_bf; j = i; }
        else if (i < N4_WIN + N4_WOUT) { src = w_out; dst = w_out_bf; j = i - N4_WIN; }
        else return;
        float4 v = ((const float4*)src)[j];
        ushort4 o;
        o.x = f2bf(v.x); o.y = f2bf(v.y); o.z = f2bf(v.z); o.w = f2bf(v.w);
        ((ushort4*)dst)[j] = o;
    }
}

// ---------------- 256x256 4-phase MFMA GEMM (gemm-in) --------------------
// C[M,N] = A[M,K] * B[N,K]^T, bf16 in.  512 thr = 8 waves (2M x 4N);
// wave tile 128x64; BK=64.  Rolling half-tile buffer, counted vmcnt(6),
// raw s_barrier.  LDS swizzle: linear dest + pre-swizzled global src.
// T1: XCD-aware block swizzle.
// EPI=2: fused RoPE+bf16 pack from acc into Qb/Kb/Vb; qkv f32 never
//   materialized.  Paired-column Q/K layout (both share the
//   d-permutation so QK^T is invariant; attention kernel unchanged).
#define LGKM(nn) asm volatile("s_waitcnt lgkmcnt(" #nn ")" ::: "memory")
#define VMC(nn)  asm volatile("s_waitcnt vmcnt(" #nn ")" ::: "memory")
#define SBAR()   __builtin_amdgcn_s_barrier()
#define SCHED0() __builtin_amdgcn_sched_barrier(0)
#define PRIO(p)  __builtin_amdgcn_s_setprio(p)

#define RD_A(mh)                                                              \
    _Pragma("unroll") for (int mi = 0; mi < 4; mi++)                          \
    _Pragma("unroll") for (int ks = 0; ks < 2; ks++)                          \
        af[mi][ks] = *(const bf16x8*)(Ab +                                    \
            ((arow0 + (mh) * 64 + mi * 16) * 8 +                              \
             ((ks * 4 + quad) ^ an)) * 8);

#define RD_B(nh)                                                              \
    _Pragma("unroll") for (int ni = 0; ni < 2; ni++)                          \
    _Pragma("unroll") for (int ks = 0; ks < 2; ks++)                          \
        bfr[nh][ni][ks] = *(const bf16x8*)(Bb +                               \
            ((brow0 + (nh) * 32 + ni * 16) * 8 +                              \
             ((ks * 4 + quad) ^ an)) * 8);

#define MMQ(mh, nh)                                                           \
    _Pragma("unroll") for (int mi = 0; mi < 4; mi++)                          \
    _Pragma("unroll") for (int ni = 0; ni < 2; ni++)                          \
    _Pragma("unroll") for (int ks = 0; ks < 2; ks++)                          \
        acc[(mh) * 4 + mi][(nh) * 2 + ni] =                                   \
            __builtin_amdgcn_mfma_f32_16x16x32_bf16(af[mi][ks],               \
                bfr[nh][ni][ks], acc[(mh) * 4 + mi][(nh) * 2 + ni],           \
                0, 0, 0);

#define ISSUE_HALF(H_)                                                        \
    {                                                                         \
        int H = (H_);                                                         \
        if (H < 4 * NT) {                                                     \
            int t2 = H >> 2, j2 = H & 3;                                      \
            int k0 = t2 << 6;                                                 \
            if (j2 == 0 || j2 == 3) {                                         \
                int half = (j2 == 3);                                         \
                ushort* lb = (ushort*)&As[t2 & 1][0];                         \
                _Pragma("unroll") for (int c = 0; c < 2; c++) {               \
                    int s = w * 2 + c;                                        \
                    int row = (s >> 3) * 128 + half * 64 + (s & 7) * 8;       \
                    const ushort* g = Aptr +                                  \
                        (size_t)(bm + row + l8) * K + k0 + kb8;               \
                    GLOBAL_TO_LDS16(g, lb + row * 64);                        \
                }                                                             \
            } else {                                                          \
                int half = (j2 == 2);                                         \
                ushort* lb = (ushort*)&Bs[t2 & 1][0];                         \
                _Pragma("unroll") for (int c = 0; c < 2; c++) {               \
                    int s = w * 2 + c;                                        \
                    int row = (s >> 2) * 64 + half * 32 + (s & 3) * 8;        \
                    const ushort* g = Bptr +                                  \
                        (size_t)(bn + row + l8) * K + k0 + kb8;               \
                    GLOBAL_TO_LDS16(g, lb + row * 64);                        \
                }                                                             \
            }                                                                 \
        }                                                                     \
    }

#define TILE(t_, BUF)                                                         \
    {                                                                         \
        const ushort* Ab = &As[BUF][0];                                       \
        const ushort* Bb = &Bs[BUF][0];                                       \
        /* phase 1: A0,B0 -> Q(0,0) */                                        \
        RD_A(0); RD_B(0);                                                     \
        ISSUE_HALF(4 * (t_) + 7);                                             \
        LGKM(8);                                                              \
        SBAR(); LGKM(0); SCHED0();                                            \
        PRIO(1); MMQ(0, 0); PRIO(0);                                          \
        SBAR();                                                               \
        /* phase 2: B1 -> Q(0,1) */                                           \
        RD_B(1);                                                              \
        ISSUE_HALF(4 * (t_) + 8);                                             \
        SBAR(); LGKM(0); SCHED0();                                            \
        PRIO(1); MMQ(0, 1); PRIO(0);                                          \
        SBAR();                                                               \
        /* phase 3: A1 -> Q(1,0) */                                           \
        RD_A(1);                                                              \
        ISSUE_HALF(4 * (t_) + 9);                                             \
        SBAR(); LGKM(0); SCHED0();                                            \
        PRIO(1); MMQ(1, 0); PRIO(0);                                          \
        SBAR();                                                               \
        /* phase 4: Q(1,1) + tile-boundary counted vmcnt */                   \
        ISSUE_HALF(4 * (t_) + 10);                                            \
        SBAR(); SCHED0();                                                     \
        PRIO(1); MMQ(1, 1); PRIO(0);                                          \
        if ((t_) + 2 < NT)        { VMC(6); }                                 \
        else if ((t_) + 2 == NT)  { VMC(0); }                                 \
        SBAR();                                                               \
    }

__global__ __launch_bounds__(512, 2) void gemm_in_8ph(
        const ushort* __restrict__ Aptr, const ushort* __restrict__ Bptr,
        ushort* __restrict__ Qb_, ushort* __restrict__ Kb_,
        ushort* __restrict__ Vb_, const float2* __restrict__ Tab,
        int M, int N, int K) {
    __shared__ __align__(16) ushort As[2][256 * 64];
    __shared__ __align__(16) ushort Bs[2][256 * 64];

    // XCD-aware swizzle: XCD k owns a contiguous chunk of tile space.
    int nwg = (int)(gridDim.x * gridDim.y);
    int lin = (int)(blockIdx.y * gridDim.x + blockIdx.x);
    int swz = (lin & 7) * (nwg >> 3) + (lin >> 3);
    const int bm = (swz / (int)gridDim.x) * 256;
    const int bn = (swz % (int)gridDim.x) * 256;

    const int w = threadIdx.x >> 6, lane = threadIdx.x & 63;
    const int n = lane & 15, quad = lane >> 4;
    const int wm = w >> 2, wn = w & 3;
    const int an = n & 7;
    const int l8 = lane >> 3;
    const int kb8 = ((lane & 7) ^ l8) * 8;
    const int arow0 = wm * 128 + n;
    const int brow0 = wn * 64 + n;
    const int NT = K >> 6;

    f32x4 acc[8][4] = {};
    bf16x8 af[4][2], bfr[2][2][2];

    // prologue: pre-issue 7 halves (queue order), land first 4, barrier
    ISSUE_HALF(0); ISSUE_HALF(1); ISSUE_HALF(2); ISSUE_HALF(3);
    ISSUE_HALF(4); ISSUE_HALF(5); ISSUE_HALF(6);
    VMC(6);
    SBAR();

    for (int tt = 0; tt < NT; tt += 2) {
        TILE(tt, 0);
        TILE(tt + 1, 1);
    }

    // ---- fused RoPE + pack epilogue ----
    const int bq = bm >> 11;           // batch (BM=256 divides 2048)
    const int s0 = bm & 2047;          // first seq pos of this block
    int col0 = bn + wn * 64;           // wave's head base (one full head)
    int slb = wm * 128 + quad * 4;
    if (col0 < CQ + CK) {
        bool isQ = col0 < CQ;
        ushort* base;
        if (isQ) {
            int head = col0 >> 6;
            base = Qb_ + ((size_t)((bq * 8 + (head >> 2)) * 4 + (head & 3))
                          * SEQ) * 64;
        } else {
            int kh = (col0 - CQ) >> 6;
            base = Kb_ + ((size_t)(bq * 8 + kh) * SEQ) * 64;
        }
        const float QS = 0.18033688011112042f;   // 0.125 * log2(e)
#pragma unroll
        for (int mi = 0; mi < 8; mi++)
#pragma unroll
            for (int r = 0; r < 4; r++) {
                int s = s0 + slb + mi * 16 + r;
                float2 t0 = Tab[(size_t)s * 32 + n];
                float2 t1 = Tab[(size_t)s * 32 + n + 16];
                float o1a = acc[mi][0][r] * t0.x - acc[mi][2][r] * t0.y;
                float o2a = acc[mi][2][r] * t0.x + acc[mi][0][r] * t0.y;
                float o1b = acc[mi][1][r] * t1.x - acc[mi][3][r] * t1.y;
                float o2b = acc[mi][3][r] * t1.x + acc[mi][1][r] * t1.y;
                if (isQ) { o1a *= QS; o2a *= QS; o1b *= QS; o2b *= QS; }
                uint* drow = (uint*)(base + (size_t)s * 64);
                drow[n]      = cvt_pk_bf16(o1a, o2a);   // cols (n, n+32)
                drow[16 + n] = cvt_pk_bf16(o1b, o2b);   // cols (n+16, n+48)
            }
    } else {
        int vh = (col0 - CQ - CK) >> 6;
        ushort* vb = Vb_ + (size_t)(bq * 8 + vh) * 64 * SEQ;
#pragma unroll
        for (int mi = 0; mi < 8; mi++)
#pragma unroll
            for (int ni = 0; ni < 4; ni++) {
                int d = ni * 16 + n;
                int s = s0 + slb + mi * 16;
                uint* dst = (uint*)(vb + (size_t)d * SEQ + s);
                dst[0] = cvt_pk_bf16(acc[mi][ni][0], acc[mi][ni][1]);
                dst[1] = cvt_pk_bf16(acc[mi][ni][2], acc[mi][ni][3]);
            }
    }
}

// ---------------- gemm-out: 128x128 tile, 2 blocks/CU --------------------
// out[t][c] = X[t][c] + sum_k o_bf[t][k]*w_out[c][k].  Operands swapped:
// A = w_out (M=DMODEL rows), B = o_bf (N=TOKENS rows), same accumulation
// chain as the previous (passing) swapped kernel -> identical numerics.
// 64 KB LDS -> 2 co-resident blocks/CU (16 waves/CU): block B's compute
// fills block A's barrier/vmcnt stalls (the m114 overlap the 1-block/CU
// variants lacked).  8 waves (2M x 4N), wave tile 64x32, BK=64.
// Double-buffer, stage t+2 after the post-read barrier, counted VMC(4).
#define OSTAGE(t_, b_)                                                        \
    {                                                                         \
        int k0 = (t_) << 6;                                                   \
        _Pragma("unroll") for (int c = 0; c < 2; c++) {                       \
            int row = c * 64 + w * 8 + l3;                                    \
            GLOBAL_TO_LDS16(Aptr + (size_t)(bm + row) * DMODEL + k0 + kx8,    \
                            &As[b_][(c * 64 + w * 8) * 64]);                  \
            GLOBAL_TO_LDS16(Bptr + (size_t)(bn + row) * DMODEL + k0 + kx8,    \
                            &Bs[b_][(c * 64 + w * 8) * 64]);                  \
        }                                                                     \
    }

__global__ __launch_bounds__(512, 4) void gemm_out_128(
        const ushort* __restrict__ Aptr,   // w_out_bf [DMODEL][DMODEL]
        const ushort* __restrict__ Bptr,   // o_bf [TOKENS][DMODEL]
        const float* __restrict__ X, float* __restrict__ OUT) {
    __shared__ __align__(16) ushort As[2][128 * 64];
    __shared__ __align__(16) ushort Bs[2][128 * 64];
    const int NT = DMODEL >> 6;

    int nwg = (int)(gridDim.x * gridDim.y);            // 512
    int lin = (int)(blockIdx.y * gridDim.x + blockIdx.x);
    int swz = (lin & 7) * (nwg >> 3) + (lin >> 3);
    const int bm = (swz / (int)gridDim.x) * 128;       // out-channel base
    const int bn = (swz % (int)gridDim.x) * 128;       // token base

    const int w = threadIdx.x >> 6, lane = threadIdx.x & 63;
    const int n = lane & 15, quad = lane >> 4;
    const int wm = w >> 2, wn = w & 3;
    const int an = n & 7;
    const int l3 = lane >> 3;
    const int kx8 = ((lane & 7) ^ l3) * 8;

    f32x4 acc[4][2] = {};
    bf16x8 af[4][2], bfr[2][2];

    OSTAGE(0, 0);
    OSTAGE(1, 1);
    VMC(4);                 // tile 0 landed (tile 1's 4 loads outstanding)
    SBAR();

    for (int t = 0; t < NT; t++) {
        int b = t & 1;
#pragma unroll
        for (int mi = 0; mi < 4; mi++)
#pragma unroll
            for (int ks = 0; ks < 2; ks++)
                af[mi][ks] = *(const bf16x8*)(&As[b][0] +
                    ((wm * 64 + mi * 16 + n) * 8 + ((ks * 4 + quad) ^ an)) * 8);
#pragma unroll
        for (int ni = 0; ni < 2; ni++)
#pragma unroll
            for (int ks = 0; ks < 2; ks++)
                bfr[ni][ks] = *(const bf16x8*)(&Bs[b][0] +
                    ((wn * 32 + ni * 16 + n) * 8 + ((ks * 4 + quad) ^ an)) * 8);
        LGKM(0);
        SBAR();             // all waves' reads of buf b done -> safe to refill
        if (t + 2 < NT) OSTAGE(t + 2, b);
        SCHED0();
        PRIO(1);
#pragma unroll
        for (int mi = 0; mi < 4; mi++)
#pragma unroll
            for (int ni = 0; ni < 2; ni++)
#pragma unroll
                for (int ks = 0; ks < 2; ks++)
                    acc[mi][ni] = __builtin_amdgcn_mfma_f32_16x16x32_bf16(
                        af[mi][ks], bfr[ni][ks], acc[mi][ni], 0, 0, 0);
        PRIO(0);
        if (t + 2 < NT)      { VMC(4); }   // wait tile t+1 (t+2 in flight)
        else if (t + 1 < NT) { VMC(0); }   // tail: drain fully
        SBAR();             // tile t+1 resident for all waves
    }

    // epilogue: acc rows = 4 consecutive out-channels, cols = tokens
#pragma unroll
    for (int mi = 0; mi < 4; mi++)
#pragma unroll
        for (int ni = 0; ni < 2; ni++) {
            int c0 = bm + wm * 64 + mi * 16 + quad * 4;
            int t  = bn + wn * 32 + ni * 16 + n;
            const float4 xv = *(const float4*)(X + (size_t)t * DMODEL + c0);
            float4 ov;
            ov.x = xv.x + acc[mi][ni][0];
            ov.y = xv.y + acc[mi][ni][1];
            ov.z = xv.z + acc[mi][ni][2];
            ov.w = xv.w + acc[mi][ni][3];
            *(float4*)(OUT + (size_t)t * DMODEL + c0) = ov;
        }
}

// ---------------- MFMA flash attention, v4 -------------------------------
// Block = (b,g,h, 128-query tile); 8 waves x 16 query rows each.
// No-max exp2 softmax (Q pre-scaled): p = v_exp(S2), l = ones-column MFMA.
// S^T via operand swap -> consecutive keys in-lane -> packed-dword P writes.
// K/V staged by direct global_load_lds, double-buffered, counted vmcnt(2).
// Conflict-free reads via XOR on the GLOBAL source (both-sides-or-neither).
// P per-wave LDS: dwords ((key>>3)*17 + q)*4 + ((key&7)>>1), q in [0,16).
// NOTE: Q and K arrive in the gemm-in epilogue's paired-column layout;
// since both share it, QK^T over d is unchanged.
#define AISSUE(kt_, buf_)                                                     \
    {                                                                         \
        const ushort* Kg_ = Kg0 + (kt_) * 64 * 64;                            \
        const ushort* Vg_ = Vg0 + (kt_) * 64;                                 \
        GLOBAL_TO_LDS16(Kg_ + (w * 8 + l3) * 64 + lx * 8,                     \
                        &Kl[buf_][(size_t)threadIdx.x * 8]);                  \
        GLOBAL_TO_LDS16(Vg_ + (size_t)(w * 8 + l3) * SEQ + lx * 8,            \
                        &Vl[buf_][(size_t)threadIdx.x * 8]);                  \
    }

__global__ __launch_bounds__(512) void attn_mfma_kernel(
        const ushort* __restrict__ Qb, const ushort* __restrict__ Kb,
        const ushort* __restrict__ Vb, ushort* __restrict__ o_bf) {
    __shared__ __align__(16) ushort Kl[2][512 * 8];
    __shared__ __align__(16) ushort Vl[2][512 * 8];
    __shared__ __align__(16) uint   Pl[8][544];

    int blk = blockIdx.x;
    int qt  = 15 - (blk >> 6);          // longest blocks dispatch first
    int bgh = blk & 63;
    int h = bgh & 3, g = (bgh >> 2) & 7, b = bgh >> 5;
    int w = threadIdx.x >> 6, lane = threadIdx.x & 63;
    int n = lane & 15, quad = lane >> 4;
    const int an = n & 7;
    int Q0 = qt * 128;
    int qw = Q0 + w * 16;               // wave's first query row

    // staging lane constants
    const int l3 = lane >> 3;
    const int lx = (lane & 7) ^ l3;

    const ushort* Qh  = Qb + (size_t)((b * 8 + g) * 4 + h) * (SEQ * 64);
    const ushort* Kg0 = Kb + (size_t)(b * 8 + g) * (SEQ * 64);
    const ushort* Vg0 = Vb + (size_t)(b * 8 + g) * (64 * SEQ);

    // Q fragments (rows of Q; per-lane data for B-operand use)
    bf16x8 aq[2];
#pragma unroll
    for (int ks = 0; ks < 2; ks++)
        aq[ks] = *(const bf16x8*)(
            Qh + (size_t)(qw + n) * 64 + ks * 32 + quad * 8);

    f32x4 od[4] = {};
    f32x4 od4 = {};

    short onev = (n == 0) ? (short)0x3F80 : (short)0;
    bf16x8 bones = {onev, onev, onev, onev, onev, onev, onev, onev};

    uint* Pw = Pl[w];
    int nkt = qt * 2 + 2;

    // prologue: tiles 0 and 1 in flight (2 loads each per lane)
    AISSUE(0, 0);
    AISSUE(1, 1);

    for (int kt = 0; kt < nkt; kt++) {
        int buf = kt & 1;
        if (kt + 1 < nkt) { VMC(2); } else { VMC(0); }
        SBAR(); SCHED0();                // buf[kt&1] fully loaded, all waves

        bool act = (kt * 64 <= qw + 15);   // do this wave's rows see kt?
        if (act) {
            const ushort* Kb_ = Kl[buf];
            const ushort* Vb_ = Vl[buf];

            // S^T = K Q^T (operand swap), exp2, cvt_pk, P write
#pragma unroll
            for (int t16k = 0; t16k < 4; t16k++) {
                int krow = (t16k * 16 + n) * 8;
                bf16x8 kf0 = *(const bf16x8*)(Kb_ + (krow + (quad ^ an)) * 8);
                bf16x8 kf1 = *(const bf16x8*)(Kb_ + (krow + ((quad + 4) ^ an)) * 8);
                int key0 = kt * 64 + t16k * 16 + quad * 4;
                f32x4 c = {};
                PRIO(1);
                c = __builtin_amdgcn_mfma_f32_16x16x32_bf16(kf0, aq[0], c, 0, 0, 0);
                c = __builtin_amdgcn_mfma_f32_16x16x32_bf16(kf1, aq[1], c, 0, 0, 0);
                PRIO(0);
                int qrow = qw + n;
                float p[4];
                if (kt * 64 + 63 > qw) {             // tile may mask
#pragma unroll
                    for (int r = 0; r < 4; r++)
                        p[r] = (key0 + r <= qrow) ? __builtin_amdgcn_exp2f(c[r]) : 0.f;
                } else {
#pragma unroll
                    for (int r = 0; r < 4; r++)
                        p[r] = __builtin_amdgcn_exp2f(c[r]);
                }
                uint d0 = cvt_pk_bf16(p[0], p[1]);
                uint d1 = cvt_pk_bf16(p[2], p[3]);
                int base = ((t16k * 2 + (quad >> 1)) * 17 + n) * 4
                           + (quad & 1) * 2;
                Pw[base]     = d0;
                Pw[base + 1] = d1;
            }

            // O += P V   (+ ones column accumulates l)
#pragma unroll
            for (int kb2 = 0; kb2 < 2; kb2++) {
                int kb = kb2 * 4 + quad;
                bf16x8 bv[4];
#pragma unroll
                for (int dt = 0; dt < 4; dt++)
                    bv[dt] = *(const bf16x8*)(Vb_ +
                        (((dt * 16 + n) * 8 + (kb ^ an)) * 8));
                bf16x8 ap = *(const bf16x8*)(
                    (const ushort*)Pw + ((kb2 * 4 + quad) * 17 + n) * 8);
                PRIO(1);
#pragma unroll
                for (int dt = 0; dt < 4; dt++)
                    od[dt] = __builtin_amdgcn_mfma_f32_16x16x32_bf16(
                        ap, bv[dt], od[dt], 0, 0, 0);
                od4 = __builtin_amdgcn_mfma_f32_16x16x32_bf16(
                    ap, bones, od4, 0, 0, 0);
                PRIO(0);
            }
        }

        SCHED0(); SBAR();                // all reads of buf done
        if (kt + 2 < nkt) AISSUE(kt + 2, buf);
    }

    // epilogue: l lives in column 0 of od4 (lane n==0); broadcast, divide
    float linv[4];
#pragma unroll
    for (int r = 0; r < 4; r++) {
        float lv = __shfl(od4[r], lane & 48);
        linv[r] = __builtin_amdgcn_rcpf(lv);
    }
#pragma unroll
    for (int dt = 0; dt < 4; dt++)
#pragma unroll
        for (int r = 0; r < 4; r++) {
            int q = qw + quad * 4 + r;
            int col = (g * 4 + h) * 64 + dt * 16 + n;
            o_bf[(size_t)(b * SEQ + q) * DMODEL + col] =
                f2bf(od[dt][r] * linv[r]);
        }
}

extern "C" void kernel_launch(void* const* d_in, const int* in_sizes, int n_in,
                              void* d_out, int out_size, void* d_ws, size_t ws_size,
                              hipStream_t stream) {
    const float* x     = (const float*)d_in[0];
    const float* w_in  = (const float*)d_in[1];
    const float* w_out = (const float*)d_in[2];
    const float* rms_w = (const float*)d_in[3];
    float* out = (float*)d_out;

    // Workspace layout (76 MB):
    //   [0,16)   Qb bf16      [16,20) Kb     [20,24) Vb
    //   [24,40)  o_bf bf16    (rope_tab f32x2 512KB aliases o_bf head:
    //                          tab live only until gemm-in ends; o_bf
    //                          written first by attention, after gemm-in)
    //   [40,48)  w_out_bf     [48,64) y_bf   [64,76) w_in_bf
    const size_t MB = 1024 * 1024;
    char* ws = (char*)d_ws;
    ushort* Qb       = (ushort*)ws;
    ushort* Kb       = (ushort*)(ws + 16 * MB);
    ushort* Vb       = (ushort*)(ws + 20 * MB);
    ushort* o_bf     = (ushort*)(ws + 24 * MB);
    float2* rope_tab = (float2*)(ws + 24 * MB);
    ushort* w_out_bf = (ushort*)(ws + 40 * MB);
    ushort* y_bf     = (ushort*)(ws + 48 * MB);
    ushort* w_in_bf  = (ushort*)(ws + 64 * MB);

    prep_kernel<<<PREP_TOTAL, 256, 0, stream>>>(
        x, rms_w, w_in, w_out, y_bf, w_in_bf, w_out_bf, rope_tab);

    // GEMM-in with fused RoPE/pack epilogue: writes Qb/Kb/Vb directly.
    gemm_in_8ph<<<dim3(CONCAT / 256, TOKENS / 256), 512, 0, stream>>>(
        y_bf, w_in_bf, Qb, Kb, Vb, rope_tab, TOKENS, CONCAT, DMODEL);

    attn_mfma_kernel<<<1024, 512, 0, stream>>>(Qb, Kb, Vb, o_bf);

    // GEMM-out: 128^2 tiles, 512 blocks = 2/CU.
    gemm_out_128<<<dim3(TOKENS / 128, DMODEL / 128), 512, 0, stream>>>(
        w_out_bf, o_bf, x, out);
}